// Round 15
// baseline (252.208 us; speedup 1.0000x reference)
//
#include <hip/hip_runtime.h>
#include <hip/hip_fp16.h>
#include <cstdint>
#include <cstddef>

// ---------------------------------------------------------------------------
// GATv2Classifier: x(N,128) -> GATv2(2 heads,64,concat) -> elu
//                 -> GATv2(1 head,64) -> elu -> mean-pool(64 graphs) -> linear(10)
// R1..R7: pool rle; CSR gather; MFMA; edge-parallel; fp16 score; deferred
//         bias/ELU + exp2 + transposed gemm stores. 1368 -> 299us.
// R8/R9: gat software pipelining; scan fixed. 289us.
// R10: bucket-CSR + merged dispatches. 234us.
// R11/R12/R13: fill ILP neutral; in-kernel device fence = +85us (reverted);
//      plateau 231us. gemm1_fill 50us: ~38MB of its 67MB WRITE is the 600k
//      cnt atomics' line-RMWs, on lines DISJOINT from the slot stores.
// R14: bucket record = 128B [int cnt | 62 x u16 slots]: atomic + slot store
//      share the same line(s) (write combining at the coherent point);
//      bucket 8->6.4MB; gat-side slot reads u16, deg+first-30-slots in one
//      line. Everything else unchanged.
// ---------------------------------------------------------------------------

typedef __attribute__((ext_vector_type(8))) short s8v;   // 8 bf16 (4 VGPRs)
typedef __attribute__((ext_vector_type(4))) float f4v;   // MFMA accumulator

#define LOG2E 1.44269504f

__device__ __forceinline__ unsigned short f2bf(float f) {
    unsigned u = __float_as_uint(f);
    unsigned r = (u + 0x7fffu + ((u >> 16) & 1u)) >> 16;   // RNE
    return (unsigned short)r;
}
__device__ __forceinline__ __half2 habs2_(__half2 x) {
    unsigned u; __builtin_memcpy(&u, &x, 4);
    u &= 0x7fff7fffu;
    __half2 r; __builtin_memcpy(&r, &u, 4);
    return r;
}
__device__ __forceinline__ float elu_(float v) {          // exp-based ELU
    return v > 0.f ? v : exp2f(v * LOG2E) - 1.f;
}
union U4H { uint4 u; __half2 h[4]; };

// ---- dual MFMA GEMM body (transposed): mfma(Wfrag,Xfrag) => D[outch][node]
template<int CO, bool ELU_A>
__device__ __forceinline__ void gemm_dual_body(
        int blk, const void* __restrict__ Aptr,
        const unsigned short* __restrict__ Wlp, const unsigned short* __restrict__ Wrp,
        __half* __restrict__ outL, __half* __restrict__ outR,
        const float* __restrict__ att, const float* __restrict__ bias_in,
        float* __restrict__ sl06, float* __restrict__ sr06, int n) {
    constexpr int NT = CO / 16;
    constexpr int H  = CO / 64;          // heads (2 layer1, 1 layer2)
    int lane = threadIdx.x & 63;
    int node0 = blk * 64 + (threadIdx.x >> 6) * 16;
    int m = lane & 15, quad = lane >> 4;
    int row = node0 + m;                 // node this lane loads AND owns in D
    s8v a[4];
#pragma unroll
    for (int ks = 0; ks < 4; ks++) {
        union { s8v v; unsigned short u[8]; } t;
        int k0 = ks * 32 + quad * 8;
        if (row < n) {
            if (ELU_A) {
                const __half* A = (const __half*)Aptr;
                U4H raw; raw.u = *(const uint4*)(A + ((unsigned)row << 7) + k0);
                float4 bA = *(const float4*)(bias_in + k0);
                float4 bB = *(const float4*)(bias_in + k0 + 4);
                float bb[8] = {bA.x, bA.y, bA.z, bA.w, bB.x, bB.y, bB.z, bB.w};
#pragma unroll
                for (int jp = 0; jp < 4; jp++) {
                    float e0 = elu_(__low2float(raw.h[jp])  + bb[jp * 2]);
                    float e1 = elu_(__high2float(raw.h[jp]) + bb[jp * 2 + 1]);
                    t.u[jp * 2]     = f2bf(e0);
                    t.u[jp * 2 + 1] = f2bf(e1);
                }
            } else {
                const float* A = (const float*)Aptr;
                float4 fA = *(const float4*)(A + ((unsigned)row << 7) + k0);
                float4 fB = *(const float4*)(A + ((unsigned)row << 7) + k0 + 4);
                t.u[0] = f2bf(fA.x); t.u[1] = f2bf(fA.y);
                t.u[2] = f2bf(fA.z); t.u[3] = f2bf(fA.w);
                t.u[4] = f2bf(fB.x); t.u[5] = f2bf(fB.y);
                t.u[6] = f2bf(fB.z); t.u[7] = f2bf(fB.w);
            }
        } else {
#pragma unroll
            for (int j = 0; j < 8; j++) t.u[j] = 0;
        }
        a[ks] = t.v;
    }
    float dl[2] = {0.f, 0.f}, dr[2] = {0.f, 0.f};   // per-head att-dot partials
#pragma unroll
    for (int ct = 0; ct < NT; ct++) {
        f4v cl = {0.f, 0.f, 0.f, 0.f}, cr = {0.f, 0.f, 0.f, 0.f};
#pragma unroll
        for (int ks = 0; ks < 4; ks++) {
            s8v bl = *(const s8v*)(Wlp + ((size_t)(ct * 4 + ks) * 64 + lane) * 8);
            s8v br = *(const s8v*)(Wrp + ((size_t)(ct * 4 + ks) * 64 + lane) * 8);
            cl = __builtin_amdgcn_mfma_f32_16x16x32_bf16(bl, a[ks], cl, 0, 0, 0);  // SWAPPED
            cr = __builtin_amdgcn_mfma_f32_16x16x32_bf16(br, a[ks], cr, 0, 0, 0);
        }
        int ch0 = ct * 16 + quad * 4;    // 4 consecutive out-channels this lane holds
        int hh = (H == 2) ? (ct >> 2) : 0;
        float4 av = *(const float4*)(att + ch0);
        dl[hh] += av.x * cl[0] + av.y * cl[1] + av.z * cl[2] + av.w * cl[3];
        dr[hh] += av.x * cr[0] + av.y * cr[1] + av.z * cr[2] + av.w * cr[3];
        if (row < n) {
            __half2 p0 = __floats2half2_rn(cl[0], cl[1]);
            __half2 p1 = __floats2half2_rn(cl[2], cl[3]);
            __half2 q0 = __floats2half2_rn(cr[0], cr[1]);
            __half2 q1 = __floats2half2_rn(cr[2], cr[3]);
            uint2 ov, orv;
            __builtin_memcpy(&ov.x, &p0, 4);  __builtin_memcpy(&ov.y, &p1, 4);
            __builtin_memcpy(&orv.x, &q0, 4); __builtin_memcpy(&orv.y, &q1, 4);
            *(uint2*)(outL + (unsigned)row * CO + ch0) = ov;
            *(uint2*)(outR + (unsigned)row * CO + ch0) = orv;
        }
    }
#pragma unroll
    for (int h = 0; h < H; h++) {
        float vl = dl[h], vr = dr[h];
        vl += __shfl_xor(vl, 16, 64); vl += __shfl_xor(vl, 32, 64);
        vr += __shfl_xor(vr, 16, 64); vr += __shfl_xor(vr, 32, 64);
        if (quad == 0 && row < n) {
            if (H == 2) {
                sl06[((unsigned)row << 1) + h] = (0.6f * LOG2E) * vl;
                sr06[((unsigned)row << 1) + h] = (0.6f * LOG2E) * vr;
            } else {
                sl06[row] = (0.6f * LOG2E) * vl;
                sr06[row] = (0.6f * LOG2E) * vr;
            }
        }
    }
}

// ---------------- d1: weight packing + zero(bucket records) + zero(pooled) --
// blocks [0,24): pack. [24, 24+zb): bucket=0 (uint4). rest: pooled/counts=0.
__global__ void pack_zero(const float* __restrict__ Wl1, const float* __restrict__ Wr1,
                          const float* __restrict__ Wl2, const float* __restrict__ Wr2,
                          unsigned short* __restrict__ Wl1p, unsigned short* __restrict__ Wr1p,
                          unsigned short* __restrict__ Wl2p, unsigned short* __restrict__ Wr2p,
                          uint4* __restrict__ bucket16, int nb16, int zb,
                          float* __restrict__ pooled, int npool) {
    int b = blockIdx.x;
    if (b >= 24) {
        if (b < 24 + zb) {
            int i = (b - 24) * 256 + threadIdx.x;
            if (i < nb16) bucket16[i] = (uint4){0, 0, 0, 0};
        } else {
            int i = (b - 24 - zb) * 256 + threadIdx.x;
            if (i < npool) pooled[i] = 0.f;
        }
        return;
    }
    int t = b * 256 + threadIdx.x;
    const float* W; unsigned short* Wp; int CO, base;
    if      (t < 2048) { W = Wl1; Wp = Wl1p; CO = 128; base = t; }
    else if (t < 4096) { W = Wr1; Wp = Wr1p; CO = 128; base = t - 2048; }
    else if (t < 5120) { W = Wl2; Wp = Wl2p; CO = 64;  base = t - 4096; }
    else               { W = Wr2; Wp = Wr2p; CO = 64;  base = t - 5120; }
    int lane = base & 63, ks = (base >> 6) & 3, ct = base >> 8;
    int col = ct * 16 + (lane & 15);
    int k0 = ks * 32 + (lane >> 4) * 8;
    unsigned short u[8];
#pragma unroll
    for (int j = 0; j < 8; j++) u[j] = f2bf(W[(size_t)(k0 + j) * CO + col]);
    unsigned* dst = (unsigned*)(Wp + (size_t)base * 8);
    dst[0] = u[0] | ((unsigned)u[1] << 16);
    dst[1] = u[2] | ((unsigned)u[3] << 16);
    dst[2] = u[4] | ((unsigned)u[5] << 16);
    dst[3] = u[6] | ((unsigned)u[7] << 16);
}

// ---------------- d2: interleaved gemm1 (even blocks) + fill (odd blocks) ---
// Record: 128B = [int cnt | u16 slots at byte 4+2j, capacity 62].
// Atomic and slot store share the record's line(s).
__global__ void gemm1_fill(const float* __restrict__ x,
                           const unsigned short* __restrict__ Wl1p,
                           const unsigned short* __restrict__ Wr1p,
                           __half* __restrict__ xl1, __half* __restrict__ xr1,
                           const float* __restrict__ att1,
                           float* __restrict__ sl1, float* __restrict__ sr1, int n,
                           int GB, int FBn,
                           const int* __restrict__ srcA, const int* __restrict__ dstA, int E,
                           int* __restrict__ bucket) {
    int b = blockIdx.x;
    if ((b & 1) == 0) {
        int g = b >> 1;
        if (g < GB)
            gemm_dual_body<128, false>(g, x, Wl1p, Wr1p, xl1, xr1,
                                       att1, nullptr, sl1, sr1, n);
        return;
    }
    int f = b >> 1;
    if (f >= FBn) return;
    int t0 = f * 256 + threadIdx.x;
    int Q = FBn * 256;
#pragma unroll
    for (int k = 0; k < 4; k++) {
        int i = t0 + k * Q;
        if (i < E) {
            int d = dstA[i];
            int* rec = bucket + d * 32;            // 128B record
            int pos = atomicAdd(rec, 1);           // deg<=~35 << 62 capacity
            ((unsigned short*)rec)[2 + pos] = (unsigned short)srcA[i];
        }
    }
}

__global__ void gemm2(const __half* __restrict__ h1,
                      const unsigned short* __restrict__ Wl2p,
                      const unsigned short* __restrict__ Wr2p,
                      __half* __restrict__ xl2, __half* __restrict__ xr2,
                      const float* __restrict__ att2, const float* __restrict__ b1,
                      float* __restrict__ sl2, float* __restrict__ sr2, int n) {
    gemm_dual_body<64, true>(blockIdx.x, h1, Wl2p, Wr2p, xl2, xr2,
                             att2, b1, sl2, sr2, n);
}

// slot accessor: clamped in-bounds read (value discarded when j out of range)
__device__ __forceinline__ int slot_(const unsigned short* sl16, int j) {
    return (int)sl16[2 + min(max(j, 0), 59)];
}

// ---------------- fused GATv2 layer 1: 4 edges/iter, 2-stage pipeline -------
__global__ void gat1_fused(const __half* __restrict__ xl, const __half* __restrict__ xr,
                           const float* __restrict__ sl06, const float* __restrict__ sr06,
                           const float* __restrict__ att,
                           const int* __restrict__ bucket,
                           __half* __restrict__ h1, int n) {
    int d = (blockIdx.x * blockDim.x + threadIdx.x) >> 6;
    if (d >= n) return;
    int lane = threadIdx.x & 63;
    int e = lane >> 4;                  // edge slot 0..3
    int h = (lane >> 3) & 1;            // head
    int off = h * 64 + (lane & 7) * 8;  // 8-channel base
    U4H xv; xv.u = *(const uint4*)(xr + (((unsigned)d << 7) + off));
    float4 aA = *(const float4*)(att + off);
    float4 aB = *(const float4*)(att + off + 4);
    const float S = 0.4f * LOG2E;
    __half2 a2[4];
    a2[0] = __floats2half2_rn(S * aA.x, S * aA.y);
    a2[1] = __floats2half2_rn(S * aA.z, S * aA.w);
    a2[2] = __floats2half2_rn(S * aB.x, S * aB.y);
    a2[3] = __floats2half2_rn(S * aB.z, S * aB.w);
    float srd = sr06[((unsigned)d << 1) + h];
    float c0 = 0.f, c1 = 0.f, c2 = 0.f, c3 = 0.f;
    float c4 = 0.f, c5 = 0.f, c6 = 0.f, c7 = 0.f, den = 0.f;
    const int* rec = bucket + d * 32;
    int deg = rec[0];
    const unsigned short* sl16 = (const unsigned short*)rec;
    int j0 = -1 + e;
    int s0 = slot_(sl16, j0); s0 = (j0 >= 0 && j0 < deg) ? s0 : d;
    int j1 = j0 + 4;
    int s1 = slot_(sl16, j1); s1 = (j1 >= 0 && j1 < deg) ? s1 : d;
    int j2 = j0 + 8;
    int s2 = slot_(sl16, j2); s2 = (j2 >= 0 && j2 < deg) ? s2 : d;
    U4H xc;  xc.u  = *(const uint4*)(xl + (((unsigned)s0 << 7) + off));
    float slc = sl06[((unsigned)s0 << 1) + h];
    U4H xn1; xn1.u = *(const uint4*)(xl + (((unsigned)s1 << 7) + off));
    float sln1 = sl06[((unsigned)s1 << 1) + h];
    for (int base = -1; base < deg; base += 4) {
        U4H xn2; xn2.u = *(const uint4*)(xl + (((unsigned)s2 << 7) + off));
        float sln2 = sl06[((unsigned)s2 << 1) + h];
        int j3 = base + 12 + e;
        int s3 = slot_(sl16, j3); s3 = (j3 >= 0 && j3 < deg) ? s3 : d;
        bool valid = (base + e) < deg;
        __half2 sc = __floats2half2_rn(0.f, 0.f);
        sc = __hfma2(a2[0], habs2_(__hadd2(xc.h[0], xv.h[0])), sc);
        sc = __hfma2(a2[1], habs2_(__hadd2(xc.h[1], xv.h[1])), sc);
        sc = __hfma2(a2[2], habs2_(__hadd2(xc.h[2], xv.h[2])), sc);
        sc = __hfma2(a2[3], habs2_(__hadd2(xc.h[3], xv.h[3])), sc);
        float v = __low2float(sc) + __high2float(sc);
        v += __shfl_xor(v, 1, 64); v += __shfl_xor(v, 2, 64); v += __shfl_xor(v, 4, 64);
        float p = valid ? exp2f(slc + srd + v) : 0.f;
        c0 = fmaf(__low2float(xc.h[0]),  p, c0);
        c1 = fmaf(__high2float(xc.h[0]), p, c1);
        c2 = fmaf(__low2float(xc.h[1]),  p, c2);
        c3 = fmaf(__high2float(xc.h[1]), p, c3);
        c4 = fmaf(__low2float(xc.h[2]),  p, c4);
        c5 = fmaf(__high2float(xc.h[2]), p, c5);
        c6 = fmaf(__low2float(xc.h[3]),  p, c6);
        c7 = fmaf(__high2float(xc.h[3]), p, c7);
        den += p;
        xc = xn1; slc = sln1; xn1 = xn2; sln1 = sln2; s2 = s3;
    }
#pragma unroll
    for (int o = 16; o <= 32; o <<= 1) {
        c0 += __shfl_xor(c0, o, 64); c1 += __shfl_xor(c1, o, 64);
        c2 += __shfl_xor(c2, o, 64); c3 += __shfl_xor(c3, o, 64);
        c4 += __shfl_xor(c4, o, 64); c5 += __shfl_xor(c5, o, 64);
        c6 += __shfl_xor(c6, o, 64); c7 += __shfl_xor(c7, o, 64);
        den += __shfl_xor(den, o, 64);
    }
    if (e == 0) {
        float r = 1.f / den;
        __half2 o0 = __floats2half2_rn(c0 * r, c1 * r);
        __half2 o1 = __floats2half2_rn(c2 * r, c3 * r);
        __half2 o2 = __floats2half2_rn(c4 * r, c5 * r);
        __half2 o3 = __floats2half2_rn(c6 * r, c7 * r);
        uint4 out;
        __builtin_memcpy(&out.x, &o0, 4); __builtin_memcpy(&out.y, &o1, 4);
        __builtin_memcpy(&out.z, &o2, 4); __builtin_memcpy(&out.w, &o3, 4);
        *(uint4*)(h1 + (((unsigned)d << 7) + off)) = out;
    }
}

// ---------------- fused GATv2 layer 2: 8 edges/iter, 2-stage pipeline -------
__global__ void gat2_fused(const __half* __restrict__ xl, const __half* __restrict__ xr,
                           const float* __restrict__ sl06, const float* __restrict__ sr06,
                           const float* __restrict__ att,
                           const int* __restrict__ bucket,
                           float* __restrict__ h2, int n) {
    int d = (blockIdx.x * blockDim.x + threadIdx.x) >> 6;
    if (d >= n) return;
    int lane = threadIdx.x & 63;
    int e = lane >> 3;                  // edge slot 0..7
    int off = (lane & 7) * 8;           // 8-channel base
    U4H xv; xv.u = *(const uint4*)(xr + (((unsigned)d << 6) + off));
    float4 aA = *(const float4*)(att + off);
    float4 aB = *(const float4*)(att + off + 4);
    const float S = 0.4f * LOG2E;
    __half2 a2[4];
    a2[0] = __floats2half2_rn(S * aA.x, S * aA.y);
    a2[1] = __floats2half2_rn(S * aA.z, S * aA.w);
    a2[2] = __floats2half2_rn(S * aB.x, S * aB.y);
    a2[3] = __floats2half2_rn(S * aB.z, S * aB.w);
    float srd = sr06[d];
    float c0 = 0.f, c1 = 0.f, c2 = 0.f, c3 = 0.f;
    float c4 = 0.f, c5 = 0.f, c6 = 0.f, c7 = 0.f, den = 0.f;
    const int* rec = bucket + d * 32;
    int deg = rec[0];
    const unsigned short* sl16 = (const unsigned short*)rec;
    int j0 = -1 + e;
    int s0 = slot_(sl16, j0); s0 = (j0 >= 0 && j0 < deg) ? s0 : d;
    int j1 = j0 + 8;
    int s1 = slot_(sl16, j1); s1 = (j1 >= 0 && j1 < deg) ? s1 : d;
    int j2 = j0 + 16;
    int s2 = slot_(sl16, j2); s2 = (j2 >= 0 && j2 < deg) ? s2 : d;
    U4H xc;  xc.u  = *(const uint4*)(xl + (((unsigned)s0 << 6) + off));
    float slc = sl06[s0];
    U4H xn1; xn1.u = *(const uint4*)(xl + (((unsigned)s1 << 6) + off));
    float sln1 = sl06[s1];
    for (int base = -1; base < deg; base += 8) {
        U4H xn2; xn2.u = *(const uint4*)(xl + (((unsigned)s2 << 6) + off));
        float sln2 = sl06[s2];
        int j3 = base + 24 + e;
        int s3 = slot_(sl16, j3); s3 = (j3 >= 0 && j3 < deg) ? s3 : d;
        bool valid = (base + e) < deg;
        __half2 sc = __floats2half2_rn(0.f, 0.f);
        sc = __hfma2(a2[0], habs2_(__hadd2(xc.h[0], xv.h[0])), sc);
        sc = __hfma2(a2[1], habs2_(__hadd2(xc.h[1], xv.h[1])), sc);
        sc = __hfma2(a2[2], habs2_(__hadd2(xc.h[2], xv.h[2])), sc);
        sc = __hfma2(a2[3], habs2_(__hadd2(xc.h[3], xv.h[3])), sc);
        float v = __low2float(sc) + __high2float(sc);
        v += __shfl_xor(v, 1, 64); v += __shfl_xor(v, 2, 64); v += __shfl_xor(v, 4, 64);
        float p = valid ? exp2f(slc + srd + v) : 0.f;
        c0 = fmaf(__low2float(xc.h[0]),  p, c0);
        c1 = fmaf(__high2float(xc.h[0]), p, c1);
        c2 = fmaf(__low2float(xc.h[1]),  p, c2);
        c3 = fmaf(__high2float(xc.h[1]), p, c3);
        c4 = fmaf(__low2float(xc.h[2]),  p, c4);
        c5 = fmaf(__high2float(xc.h[2]), p, c5);
        c6 = fmaf(__low2float(xc.h[3]),  p, c6);
        c7 = fmaf(__high2float(xc.h[3]), p, c7);
        den += p;
        xc = xn1; slc = sln1; xn1 = xn2; sln1 = sln2; s2 = s3;
    }
#pragma unroll
    for (int o = 8; o <= 32; o <<= 1) {
        c0 += __shfl_xor(c0, o, 64); c1 += __shfl_xor(c1, o, 64);
        c2 += __shfl_xor(c2, o, 64); c3 += __shfl_xor(c3, o, 64);
        c4 += __shfl_xor(c4, o, 64); c5 += __shfl_xor(c5, o, 64);
        c6 += __shfl_xor(c6, o, 64); c7 += __shfl_xor(c7, o, 64);
        den += __shfl_xor(den, o, 64);
    }
    if (e == 0) {
        float r = 1.f / den;
        float4 A = {c0 * r, c1 * r, c2 * r, c3 * r};
        float4 B = {c4 * r, c5 * r, c6 * r, c7 * r};
        *(float4*)(h2 + (((unsigned)d << 6) + off))     = A;
        *(float4*)(h2 + (((unsigned)d << 6) + off + 4)) = B;
    }
}

// mean-pool over sorted batch; applies deferred elu(h + b2) while reading.
__global__ void pool_rle(const float* __restrict__ h, const float* __restrict__ b2,
                         const int* __restrict__ batch,
                         int n, int chunk, float* __restrict__ pooled,
                         float* __restrict__ counts) {
    int w = (blockIdx.x * blockDim.x + threadIdx.x) >> 6;
    int lane = threadIdx.x & 63;
    int start = w * chunk;
    int end = min(n, start + chunk);
    if (start >= end) return;
    float bv = b2[lane];
    int cur = batch[start];
    float acc = 0.f, cnt = 0.f;
    for (int node = start; node < end; node++) {
        int g = batch[node];
        if (g != cur) {
            atomicAdd(&pooled[(size_t)cur * 64 + lane], acc);
            if (lane == 0) atomicAdd(&counts[cur], cnt);
            acc = 0.f; cnt = 0.f; cur = g;
        }
        acc += elu_(h[((unsigned)node << 6) + lane] + bv);
        cnt += 1.f;
    }
    atomicAdd(&pooled[(size_t)cur * 64 + lane], acc);
    if (lane == 0) atomicAdd(&counts[cur], cnt);
}

__global__ void head(const float* __restrict__ pooled, const float* __restrict__ counts,
                     const float* __restrict__ Wlin, const float* __restrict__ blin,
                     float* __restrict__ out, int NC) {
    int g = blockIdx.x;
    int lane = threadIdx.x;
    float cnt = fmaxf(counts[g], 1.f);
    float v = pooled[(size_t)g * 64 + lane] / cnt;
    for (int j = 0; j < NC; j++) {
        float t = v * Wlin[lane * NC + j];
        for (int off = 32; off > 0; off >>= 1) t += __shfl_down(t, off, 64);
        if (lane == 0) out[g * NC + j] = t + blin[j];
    }
}

extern "C" void kernel_launch(void* const* d_in, const int* in_sizes, int n_in,
                              void* d_out, int out_size, void* d_ws, size_t ws_size,
                              hipStream_t stream) {
    const float* x    = (const float*)d_in[0];
    const int*   ei   = (const int*)d_in[1];
    const int*   batch= (const int*)d_in[2];
    const float* Wl1  = (const float*)d_in[3];
    const float* Wr1  = (const float*)d_in[4];
    const float* att1 = (const float*)d_in[5];
    const float* b1   = (const float*)d_in[6];
    const float* Wl2  = (const float*)d_in[7];
    const float* Wr2  = (const float*)d_in[8];
    const float* att2 = (const float*)d_in[9];
    const float* b2   = (const float*)d_in[10];
    const float* Wlin = (const float*)d_in[11];
    const float* blin = (const float*)d_in[12];

    const int n    = in_sizes[0] / 128;   // 50000
    const int E    = in_sizes[1] / 2;     // 600000
    const int NC   = in_sizes[12];        // 10
    const int NG   = out_size / NC;       // 64

    const int* srcA = ei;
    const int* dstA = ei + E;

    // ---- workspace layout (bytes). Aliasing: xl2+xr2 fill xl1's region,
    //      h2 fills xr1's. h1 (fp16) is kept live through gemm2.
    uint8_t* w = (uint8_t*)d_ws;
    const size_t rowB = (size_t)n * 128 * 2;     // one N x 128 16-bit tensor
    __half*         xl1 = (__half*)w;
    __half*         xr1 = (__half*)(w + rowB);
    __half*         h1  = (__half*)(w + 2 * rowB);
    __half*         xl2 = (__half*)w;                           // n*64 fp16
    __half*         xr2 = (__half*)(w + (size_t)n * 64 * 2);
    float*          h2  = (float*)(w + rowB);                   // n*64 fp32
    uint8_t* fx = w + 3 * rowB;
    unsigned short* Wl1p = (unsigned short*)fx;            fx += 16384 * 2;
    unsigned short* Wr1p = (unsigned short*)fx;            fx += 16384 * 2;
    unsigned short* Wl2p = (unsigned short*)fx;            fx += 8192 * 2;
    unsigned short* Wr2p = (unsigned short*)fx;            fx += 8192 * 2;
    float* sl1 = (float*)fx;                               fx += (size_t)n * 2 * 4;
    float* sr1 = (float*)fx;                               fx += (size_t)n * 2 * 4;
    float* sl2 = (float*)fx;                               fx += (size_t)n * 4;
    float* sr2 = (float*)fx;                               fx += (size_t)n * 4;
    float* pooled = (float*)fx;                            fx += (size_t)NG * 64 * 4;
    float* counts = (float*)fx;                            fx += (size_t)NG * 4;
    fx = (uint8_t*)(((uintptr_t)fx + 127) & ~(uintptr_t)127);   // 128B-align records
    int* bucket = (int*)fx;                                fx += (size_t)n * 128 + 128;
    if (ws_size < (size_t)(fx - (uint8_t*)d_ws)) return;   // bail visibly

    const int GB  = (n + 63) / 64;       // gemm blocks (64 nodes each)
    const int FBn = (E + 1023) / 1024;   // fill blocks (4 edges/thread)
    const int nb16 = n * 8;              // bucket region in uint4 units (n*128B/16)
    const int zb  = (nb16 + 255) / 256;
    const int npool = NG * 65;           // pooled + counts (contiguous)
    const int pzb = (npool + 255) / 256;
    const int dblocks = (n + 3) / 4;     // 4 dst-waves per 256-thread block
    const int T2 = 2 * ((GB > FBn) ? GB : FBn);

    // d1: pack weights + zero bucket records + zero pooled/counts
    pack_zero<<<24 + zb + pzb, 256, 0, stream>>>(Wl1, Wr1, Wl2, Wr2,
                                                 Wl1p, Wr1p, Wl2p, Wr2p,
                                                 (uint4*)bucket, nb16, zb,
                                                 pooled, npool);
    // d2: gemm layer-1 || bucket fill, interleaved even/odd
    gemm1_fill<<<T2, 256, 0, stream>>>(x, Wl1p, Wr1p, xl1, xr1, att1,
                                       sl1, sr1, n, GB, FBn,
                                       srcA, dstA, E, bucket);
    // d3..d7
    gat1_fused<<<dblocks, 256, 0, stream>>>(xl1, xr1, sl1, sr1, att1,
                                            bucket, h1, n);
    gemm2<<<GB, 256, 0, stream>>>(h1, Wl2p, Wr2p, xl2, xr2, att2, b1, sl2, sr2, n);
    gat2_fused<<<dblocks, 256, 0, stream>>>(xl2, xr2, sl2, sr2, att2,
                                            bucket, h2, n);
    {
        const int nwaves = 1024;
        const int chunk = (n + nwaves - 1) / nwaves;
        pool_rle<<<256, 256, 0, stream>>>(h2, b2, batch, n, chunk, pooled, counts);
    }
    head<<<NG, 64, 0, stream>>>(pooled, counts, Wlin, blin, (float*)d_out, NC);
}

// Round 16
// 232.735 us; speedup vs baseline: 1.0837x; 1.0837x over previous
//
#include <hip/hip_runtime.h>
#include <hip/hip_fp16.h>
#include <cstdint>
#include <cstddef>

// ---------------------------------------------------------------------------
// GATv2Classifier: x(N,128) -> GATv2(2 heads,64,concat) -> elu
//                 -> GATv2(1 head,64) -> elu -> mean-pool(64 graphs) -> linear(10)
// R1..R7: pool rle; CSR gather; MFMA; edge-parallel; fp16 score; deferred
//         bias/ELU + exp2 + transposed gemm stores. 1368 -> 299us.
// R8/R9: gat software pipelining; scan fixed. 289us.
// R10: bucket-CSR + merged dispatches. 234us.
// R11: fill ILP + interleave. NEUTRAL (fill = scatter write-amp floor).
// R12: in-kernel device fence fusion: +85us (cross-XCD L2 writeback). REVERTED.
// R13: best state: 230.9us. cnt spread 1-per-64B-line, bucket BCAP=40 int
//      slots, interleaved gemm1|fill, 2-stage pipelined gats, fp16 h1.
// R14: 128B co-located [cnt|u16 slots] record: REGRESSED 252us -- plain
//      stores into the line the atomic owns = ownership ping-pong at the
//      coherent point (WRITE unchanged; R14's write-accounting theory wrong).
// R15: exact revert to R13. Plateau check: every kernel <30% on all pipes
//      (scatter/latency/launch-bound); five structural probes neutral/neg.
// ---------------------------------------------------------------------------

typedef __attribute__((ext_vector_type(8))) short s8v;   // 8 bf16 (4 VGPRs)
typedef __attribute__((ext_vector_type(4))) float f4v;   // MFMA accumulator

#define LOG2E 1.44269504f
#define BCAP 40                         // bucket slots per dst

__device__ __forceinline__ unsigned short f2bf(float f) {
    unsigned u = __float_as_uint(f);
    unsigned r = (u + 0x7fffu + ((u >> 16) & 1u)) >> 16;   // RNE
    return (unsigned short)r;
}
__device__ __forceinline__ __half2 habs2_(__half2 x) {
    unsigned u; __builtin_memcpy(&u, &x, 4);
    u &= 0x7fff7fffu;
    __half2 r; __builtin_memcpy(&r, &u, 4);
    return r;
}
__device__ __forceinline__ float elu_(float v) {          // exp-based ELU
    return v > 0.f ? v : exp2f(v * LOG2E) - 1.f;
}
union U4H { uint4 u; __half2 h[4]; };

// ---- dual MFMA GEMM body (transposed): mfma(Wfrag,Xfrag) => D[outch][node]
template<int CO, bool ELU_A>
__device__ __forceinline__ void gemm_dual_body(
        int blk, const void* __restrict__ Aptr,
        const unsigned short* __restrict__ Wlp, const unsigned short* __restrict__ Wrp,
        __half* __restrict__ outL, __half* __restrict__ outR,
        const float* __restrict__ att, const float* __restrict__ bias_in,
        float* __restrict__ sl06, float* __restrict__ sr06, int n) {
    constexpr int NT = CO / 16;
    constexpr int H  = CO / 64;          // heads (2 layer1, 1 layer2)
    int lane = threadIdx.x & 63;
    int node0 = blk * 64 + (threadIdx.x >> 6) * 16;
    int m = lane & 15, quad = lane >> 4;
    int row = node0 + m;                 // node this lane loads AND owns in D
    s8v a[4];
#pragma unroll
    for (int ks = 0; ks < 4; ks++) {
        union { s8v v; unsigned short u[8]; } t;
        int k0 = ks * 32 + quad * 8;
        if (row < n) {
            if (ELU_A) {
                const __half* A = (const __half*)Aptr;
                U4H raw; raw.u = *(const uint4*)(A + ((unsigned)row << 7) + k0);
                float4 bA = *(const float4*)(bias_in + k0);
                float4 bB = *(const float4*)(bias_in + k0 + 4);
                float bb[8] = {bA.x, bA.y, bA.z, bA.w, bB.x, bB.y, bB.z, bB.w};
#pragma unroll
                for (int jp = 0; jp < 4; jp++) {
                    float e0 = elu_(__low2float(raw.h[jp])  + bb[jp * 2]);
                    float e1 = elu_(__high2float(raw.h[jp]) + bb[jp * 2 + 1]);
                    t.u[jp * 2]     = f2bf(e0);
                    t.u[jp * 2 + 1] = f2bf(e1);
                }
            } else {
                const float* A = (const float*)Aptr;
                float4 fA = *(const float4*)(A + ((unsigned)row << 7) + k0);
                float4 fB = *(const float4*)(A + ((unsigned)row << 7) + k0 + 4);
                t.u[0] = f2bf(fA.x); t.u[1] = f2bf(fA.y);
                t.u[2] = f2bf(fA.z); t.u[3] = f2bf(fA.w);
                t.u[4] = f2bf(fB.x); t.u[5] = f2bf(fB.y);
                t.u[6] = f2bf(fB.z); t.u[7] = f2bf(fB.w);
            }
        } else {
#pragma unroll
            for (int j = 0; j < 8; j++) t.u[j] = 0;
        }
        a[ks] = t.v;
    }
    float dl[2] = {0.f, 0.f}, dr[2] = {0.f, 0.f};   // per-head att-dot partials
#pragma unroll
    for (int ct = 0; ct < NT; ct++) {
        f4v cl = {0.f, 0.f, 0.f, 0.f}, cr = {0.f, 0.f, 0.f, 0.f};
#pragma unroll
        for (int ks = 0; ks < 4; ks++) {
            s8v bl = *(const s8v*)(Wlp + ((size_t)(ct * 4 + ks) * 64 + lane) * 8);
            s8v br = *(const s8v*)(Wrp + ((size_t)(ct * 4 + ks) * 64 + lane) * 8);
            cl = __builtin_amdgcn_mfma_f32_16x16x32_bf16(bl, a[ks], cl, 0, 0, 0);  // SWAPPED
            cr = __builtin_amdgcn_mfma_f32_16x16x32_bf16(br, a[ks], cr, 0, 0, 0);
        }
        int ch0 = ct * 16 + quad * 4;    // 4 consecutive out-channels this lane holds
        int hh = (H == 2) ? (ct >> 2) : 0;
        float4 av = *(const float4*)(att + ch0);
        dl[hh] += av.x * cl[0] + av.y * cl[1] + av.z * cl[2] + av.w * cl[3];
        dr[hh] += av.x * cr[0] + av.y * cr[1] + av.z * cr[2] + av.w * cr[3];
        if (row < n) {
            __half2 p0 = __floats2half2_rn(cl[0], cl[1]);
            __half2 p1 = __floats2half2_rn(cl[2], cl[3]);
            __half2 q0 = __floats2half2_rn(cr[0], cr[1]);
            __half2 q1 = __floats2half2_rn(cr[2], cr[3]);
            uint2 ov, orv;
            __builtin_memcpy(&ov.x, &p0, 4);  __builtin_memcpy(&ov.y, &p1, 4);
            __builtin_memcpy(&orv.x, &q0, 4); __builtin_memcpy(&orv.y, &q1, 4);
            *(uint2*)(outL + (unsigned)row * CO + ch0) = ov;
            *(uint2*)(outR + (unsigned)row * CO + ch0) = orv;
        }
    }
#pragma unroll
    for (int h = 0; h < H; h++) {
        float vl = dl[h], vr = dr[h];
        vl += __shfl_xor(vl, 16, 64); vl += __shfl_xor(vl, 32, 64);
        vr += __shfl_xor(vr, 16, 64); vr += __shfl_xor(vr, 32, 64);
        if (quad == 0 && row < n) {
            if (H == 2) {
                sl06[((unsigned)row << 1) + h] = (0.6f * LOG2E) * vl;
                sr06[((unsigned)row << 1) + h] = (0.6f * LOG2E) * vr;
            } else {
                sl06[row] = (0.6f * LOG2E) * vl;
                sr06[row] = (0.6f * LOG2E) * vr;
            }
        }
    }
}

// ---------------- d1: weight packing + zero(cnt,spread) + zero(pooled) ------
__global__ void pack_zero(const float* __restrict__ Wl1, const float* __restrict__ Wr1,
                          const float* __restrict__ Wl2, const float* __restrict__ Wr2,
                          unsigned short* __restrict__ Wl1p, unsigned short* __restrict__ Wr1p,
                          unsigned short* __restrict__ Wl2p, unsigned short* __restrict__ Wr2p,
                          int* __restrict__ cnt, int ncnt, int zcb,
                          float* __restrict__ pooled, int npool) {
    int b = blockIdx.x;
    if (b >= 24) {
        if (b < 24 + zcb) {
            int i = (b - 24) * 256 + threadIdx.x;
            if (i < ncnt) cnt[i] = 0;
        } else {
            int i = (b - 24 - zcb) * 256 + threadIdx.x;
            if (i < npool) pooled[i] = 0.f;
        }
        return;
    }
    int t = b * 256 + threadIdx.x;
    const float* W; unsigned short* Wp; int CO, base;
    if      (t < 2048) { W = Wl1; Wp = Wl1p; CO = 128; base = t; }
    else if (t < 4096) { W = Wr1; Wp = Wr1p; CO = 128; base = t - 2048; }
    else if (t < 5120) { W = Wl2; Wp = Wl2p; CO = 64;  base = t - 4096; }
    else               { W = Wr2; Wp = Wr2p; CO = 64;  base = t - 5120; }
    int lane = base & 63, ks = (base >> 6) & 3, ct = base >> 8;
    int col = ct * 16 + (lane & 15);
    int k0 = ks * 32 + (lane >> 4) * 8;
    unsigned short u[8];
#pragma unroll
    for (int j = 0; j < 8; j++) u[j] = f2bf(W[(size_t)(k0 + j) * CO + col]);
    unsigned* dst = (unsigned*)(Wp + (size_t)base * 8);
    dst[0] = u[0] | ((unsigned)u[1] << 16);
    dst[1] = u[2] | ((unsigned)u[3] << 16);
    dst[2] = u[4] | ((unsigned)u[5] << 16);
    dst[3] = u[6] | ((unsigned)u[7] << 16);
}

// ---------------- d2: interleaved gemm1 (even blocks) + fill (odd blocks) ---
__global__ void gemm1_fill(const float* __restrict__ x,
                           const unsigned short* __restrict__ Wl1p,
                           const unsigned short* __restrict__ Wr1p,
                           __half* __restrict__ xl1, __half* __restrict__ xr1,
                           const float* __restrict__ att1,
                           float* __restrict__ sl1, float* __restrict__ sr1, int n,
                           int GB, int FBn,
                           const int* __restrict__ srcA, const int* __restrict__ dstA, int E,
                           int* __restrict__ cnt, int* __restrict__ bucket) {
    int b = blockIdx.x;
    if ((b & 1) == 0) {
        int g = b >> 1;
        if (g < GB)
            gemm_dual_body<128, false>(g, x, Wl1p, Wr1p, xl1, xr1,
                                       att1, nullptr, sl1, sr1, n);
        return;
    }
    int f = b >> 1;
    if (f >= FBn) return;
    int t0 = f * 256 + threadIdx.x;
    int Q = FBn * 256;
#pragma unroll
    for (int k = 0; k < 4; k++) {
        int i = t0 + k * Q;
        if (i < E) {
            int d = dstA[i];
            int pos = atomicAdd(&cnt[d << 4], 1);   // deg<=~35 < BCAP
            bucket[d * BCAP + pos] = srcA[i];
        }
    }
}

__global__ void gemm2(const __half* __restrict__ h1,
                      const unsigned short* __restrict__ Wl2p,
                      const unsigned short* __restrict__ Wr2p,
                      __half* __restrict__ xl2, __half* __restrict__ xr2,
                      const float* __restrict__ att2, const float* __restrict__ b1,
                      float* __restrict__ sl2, float* __restrict__ sr2, int n) {
    gemm_dual_body<64, true>(blockIdx.x, h1, Wl2p, Wr2p, xl2, xr2,
                             att2, b1, sl2, sr2, n);
}

// ---------------- fused GATv2 layer 1: 4 edges/iter, 2-stage pipeline -------
__global__ void gat1_fused(const __half* __restrict__ xl, const __half* __restrict__ xr,
                           const float* __restrict__ sl06, const float* __restrict__ sr06,
                           const float* __restrict__ att,
                           const int* __restrict__ cnt, const int* __restrict__ bucket,
                           __half* __restrict__ h1, int n) {
    int d = (blockIdx.x * blockDim.x + threadIdx.x) >> 6;
    if (d >= n) return;
    int lane = threadIdx.x & 63;
    int e = lane >> 4;                  // edge slot 0..3
    int h = (lane >> 3) & 1;            // head
    int off = h * 64 + (lane & 7) * 8;  // 8-channel base
    U4H xv; xv.u = *(const uint4*)(xr + (((unsigned)d << 7) + off));
    float4 aA = *(const float4*)(att + off);
    float4 aB = *(const float4*)(att + off + 4);
    const float S = 0.4f * LOG2E;
    __half2 a2[4];
    a2[0] = __floats2half2_rn(S * aA.x, S * aA.y);
    a2[1] = __floats2half2_rn(S * aA.z, S * aA.w);
    a2[2] = __floats2half2_rn(S * aB.x, S * aB.y);
    a2[3] = __floats2half2_rn(S * aB.z, S * aB.w);
    float srd = sr06[((unsigned)d << 1) + h];
    float c0 = 0.f, c1 = 0.f, c2 = 0.f, c3 = 0.f;
    float c4 = 0.f, c5 = 0.f, c6 = 0.f, c7 = 0.f, den = 0.f;
    int deg = cnt[d << 4];
    int bb = d * BCAP;
    int j0 = -1 + e;
    int s0 = bucket[bb + max(j0, 0)];               s0 = (j0 >= 0 && j0 < deg) ? s0 : d;
    int j1 = j0 + 4;
    int s1 = bucket[bb + min(max(j1, 0), BCAP - 1)]; s1 = (j1 >= 0 && j1 < deg) ? s1 : d;
    int j2 = j0 + 8;
    int s2 = bucket[bb + min(max(j2, 0), BCAP - 1)]; s2 = (j2 >= 0 && j2 < deg) ? s2 : d;
    U4H xc;  xc.u  = *(const uint4*)(xl + (((unsigned)s0 << 7) + off));
    float slc = sl06[((unsigned)s0 << 1) + h];
    U4H xn1; xn1.u = *(const uint4*)(xl + (((unsigned)s1 << 7) + off));
    float sln1 = sl06[((unsigned)s1 << 1) + h];
    for (int base = -1; base < deg; base += 4) {
        U4H xn2; xn2.u = *(const uint4*)(xl + (((unsigned)s2 << 7) + off));
        float sln2 = sl06[((unsigned)s2 << 1) + h];
        int j3 = base + 12 + e;
        int s3 = bucket[bb + min(max(j3, 0), BCAP - 1)];
        s3 = (j3 >= 0 && j3 < deg) ? s3 : d;
        bool valid = (base + e) < deg;
        __half2 sc = __floats2half2_rn(0.f, 0.f);
        sc = __hfma2(a2[0], habs2_(__hadd2(xc.h[0], xv.h[0])), sc);
        sc = __hfma2(a2[1], habs2_(__hadd2(xc.h[1], xv.h[1])), sc);
        sc = __hfma2(a2[2], habs2_(__hadd2(xc.h[2], xv.h[2])), sc);
        sc = __hfma2(a2[3], habs2_(__hadd2(xc.h[3], xv.h[3])), sc);
        float v = __low2float(sc) + __high2float(sc);
        v += __shfl_xor(v, 1, 64); v += __shfl_xor(v, 2, 64); v += __shfl_xor(v, 4, 64);
        float p = valid ? exp2f(slc + srd + v) : 0.f;
        c0 = fmaf(__low2float(xc.h[0]),  p, c0);
        c1 = fmaf(__high2float(xc.h[0]), p, c1);
        c2 = fmaf(__low2float(xc.h[1]),  p, c2);
        c3 = fmaf(__high2float(xc.h[1]), p, c3);
        c4 = fmaf(__low2float(xc.h[2]),  p, c4);
        c5 = fmaf(__high2float(xc.h[2]), p, c5);
        c6 = fmaf(__low2float(xc.h[3]),  p, c6);
        c7 = fmaf(__high2float(xc.h[3]), p, c7);
        den += p;
        xc = xn1; slc = sln1; xn1 = xn2; sln1 = sln2; s2 = s3;
    }
#pragma unroll
    for (int o = 16; o <= 32; o <<= 1) {
        c0 += __shfl_xor(c0, o, 64); c1 += __shfl_xor(c1, o, 64);
        c2 += __shfl_xor(c2, o, 64); c3 += __shfl_xor(c3, o, 64);
        c4 += __shfl_xor(c4, o, 64); c5 += __shfl_xor(c5, o, 64);
        c6 += __shfl_xor(c6, o, 64); c7 += __shfl_xor(c7, o, 64);
        den += __shfl_xor(den, o, 64);
    }
    if (e == 0) {
        float r = 1.f / den;
        __half2 o0 = __floats2half2_rn(c0 * r, c1 * r);
        __half2 o1 = __floats2half2_rn(c2 * r, c3 * r);
        __half2 o2 = __floats2half2_rn(c4 * r, c5 * r);
        __half2 o3 = __floats2half2_rn(c6 * r, c7 * r);
        uint4 out;
        __builtin_memcpy(&out.x, &o0, 4); __builtin_memcpy(&out.y, &o1, 4);
        __builtin_memcpy(&out.z, &o2, 4); __builtin_memcpy(&out.w, &o3, 4);
        *(uint4*)(h1 + (((unsigned)d << 7) + off)) = out;
    }
}

// ---------------- fused GATv2 layer 2: 8 edges/iter, 2-stage pipeline -------
__global__ void gat2_fused(const __half* __restrict__ xl, const __half* __restrict__ xr,
                           const float* __restrict__ sl06, const float* __restrict__ sr06,
                           const float* __restrict__ att,
                           const int* __restrict__ cnt, const int* __restrict__ bucket,
                           float* __restrict__ h2, int n) {
    int d = (blockIdx.x * blockDim.x + threadIdx.x) >> 6;
    if (d >= n) return;
    int lane = threadIdx.x & 63;
    int e = lane >> 3;                  // edge slot 0..7
    int off = (lane & 7) * 8;           // 8-channel base
    U4H xv; xv.u = *(const uint4*)(xr + (((unsigned)d << 6) + off));
    float4 aA = *(const float4*)(att + off);
    float4 aB = *(const float4*)(att + off + 4);
    const float S = 0.4f * LOG2E;
    __half2 a2[4];
    a2[0] = __floats2half2_rn(S * aA.x, S * aA.y);
    a2[1] = __floats2half2_rn(S * aA.z, S * aA.w);
    a2[2] = __floats2half2_rn(S * aB.x, S * aB.y);
    a2[3] = __floats2half2_rn(S * aB.z, S * aB.w);
    float srd = sr06[d];
    float c0 = 0.f, c1 = 0.f, c2 = 0.f, c3 = 0.f;
    float c4 = 0.f, c5 = 0.f, c6 = 0.f, c7 = 0.f, den = 0.f;
    int deg = cnt[d << 4];
    int bb = d * BCAP;
    int j0 = -1 + e;
    int s0 = bucket[bb + max(j0, 0)];               s0 = (j0 >= 0 && j0 < deg) ? s0 : d;
    int j1 = j0 + 8;
    int s1 = bucket[bb + min(max(j1, 0), BCAP - 1)]; s1 = (j1 >= 0 && j1 < deg) ? s1 : d;
    int j2 = j0 + 16;
    int s2 = bucket[bb + min(max(j2, 0), BCAP - 1)]; s2 = (j2 >= 0 && j2 < deg) ? s2 : d;
    U4H xc;  xc.u  = *(const uint4*)(xl + (((unsigned)s0 << 6) + off));
    float slc = sl06[s0];
    U4H xn1; xn1.u = *(const uint4*)(xl + (((unsigned)s1 << 6) + off));
    float sln1 = sl06[s1];
    for (int base = -1; base < deg; base += 8) {
        U4H xn2; xn2.u = *(const uint4*)(xl + (((unsigned)s2 << 6) + off));
        float sln2 = sl06[s2];
        int j3 = base + 24 + e;
        int s3 = bucket[bb + min(max(j3, 0), BCAP - 1)];
        s3 = (j3 >= 0 && j3 < deg) ? s3 : d;
        bool valid = (base + e) < deg;
        __half2 sc = __floats2half2_rn(0.f, 0.f);
        sc = __hfma2(a2[0], habs2_(__hadd2(xc.h[0], xv.h[0])), sc);
        sc = __hfma2(a2[1], habs2_(__hadd2(xc.h[1], xv.h[1])), sc);
        sc = __hfma2(a2[2], habs2_(__hadd2(xc.h[2], xv.h[2])), sc);
        sc = __hfma2(a2[3], habs2_(__hadd2(xc.h[3], xv.h[3])), sc);
        float v = __low2float(sc) + __high2float(sc);
        v += __shfl_xor(v, 1, 64); v += __shfl_xor(v, 2, 64); v += __shfl_xor(v, 4, 64);
        float p = valid ? exp2f(slc + srd + v) : 0.f;
        c0 = fmaf(__low2float(xc.h[0]),  p, c0);
        c1 = fmaf(__high2float(xc.h[0]), p, c1);
        c2 = fmaf(__low2float(xc.h[1]),  p, c2);
        c3 = fmaf(__high2float(xc.h[1]), p, c3);
        c4 = fmaf(__low2float(xc.h[2]),  p, c4);
        c5 = fmaf(__high2float(xc.h[2]), p, c5);
        c6 = fmaf(__low2float(xc.h[3]),  p, c6);
        c7 = fmaf(__high2float(xc.h[3]), p, c7);
        den += p;
        xc = xn1; slc = sln1; xn1 = xn2; sln1 = sln2; s2 = s3;
    }
#pragma unroll
    for (int o = 8; o <= 32; o <<= 1) {
        c0 += __shfl_xor(c0, o, 64); c1 += __shfl_xor(c1, o, 64);
        c2 += __shfl_xor(c2, o, 64); c3 += __shfl_xor(c3, o, 64);
        c4 += __shfl_xor(c4, o, 64); c5 += __shfl_xor(c5, o, 64);
        c6 += __shfl_xor(c6, o, 64); c7 += __shfl_xor(c7, o, 64);
        den += __shfl_xor(den, o, 64);
    }
    if (e == 0) {
        float r = 1.f / den;
        float4 A = {c0 * r, c1 * r, c2 * r, c3 * r};
        float4 B = {c4 * r, c5 * r, c6 * r, c7 * r};
        *(float4*)(h2 + (((unsigned)d << 6) + off))     = A;
        *(float4*)(h2 + (((unsigned)d << 6) + off + 4)) = B;
    }
}

// mean-pool over sorted batch; applies deferred elu(h + b2) while reading.
__global__ void pool_rle(const float* __restrict__ h, const float* __restrict__ b2,
                         const int* __restrict__ batch,
                         int n, int chunk, float* __restrict__ pooled,
                         float* __restrict__ counts) {
    int w = (blockIdx.x * blockDim.x + threadIdx.x) >> 6;
    int lane = threadIdx.x & 63;
    int start = w * chunk;
    int end = min(n, start + chunk);
    if (start >= end) return;
    float bv = b2[lane];
    int cur = batch[start];
    float acc = 0.f, cnt = 0.f;
    for (int node = start; node < end; node++) {
        int g = batch[node];
        if (g != cur) {
            atomicAdd(&pooled[(size_t)cur * 64 + lane], acc);
            if (lane == 0) atomicAdd(&counts[cur], cnt);
            acc = 0.f; cnt = 0.f; cur = g;
        }
        acc += elu_(h[((unsigned)node << 6) + lane] + bv);
        cnt += 1.f;
    }
    atomicAdd(&pooled[(size_t)cur * 64 + lane], acc);
    if (lane == 0) atomicAdd(&counts[cur], cnt);
}

__global__ void head(const float* __restrict__ pooled, const float* __restrict__ counts,
                     const float* __restrict__ Wlin, const float* __restrict__ blin,
                     float* __restrict__ out, int NC) {
    int g = blockIdx.x;
    int lane = threadIdx.x;
    float cnt = fmaxf(counts[g], 1.f);
    float v = pooled[(size_t)g * 64 + lane] / cnt;
    for (int j = 0; j < NC; j++) {
        float t = v * Wlin[lane * NC + j];
        for (int off = 32; off > 0; off >>= 1) t += __shfl_down(t, off, 64);
        if (lane == 0) out[g * NC + j] = t + blin[j];
    }
}

extern "C" void kernel_launch(void* const* d_in, const int* in_sizes, int n_in,
                              void* d_out, int out_size, void* d_ws, size_t ws_size,
                              hipStream_t stream) {
    const float* x    = (const float*)d_in[0];
    const int*   ei   = (const int*)d_in[1];
    const int*   batch= (const int*)d_in[2];
    const float* Wl1  = (const float*)d_in[3];
    const float* Wr1  = (const float*)d_in[4];
    const float* att1 = (const float*)d_in[5];
    const float* b1   = (const float*)d_in[6];
    const float* Wl2  = (const float*)d_in[7];
    const float* Wr2  = (const float*)d_in[8];
    const float* att2 = (const float*)d_in[9];
    const float* b2   = (const float*)d_in[10];
    const float* Wlin = (const float*)d_in[11];
    const float* blin = (const float*)d_in[12];

    const int n    = in_sizes[0] / 128;   // 50000
    const int E    = in_sizes[1] / 2;     // 600000
    const int NC   = in_sizes[12];        // 10
    const int NG   = out_size / NC;       // 64

    const int* srcA = ei;
    const int* dstA = ei + E;

    // ---- workspace layout (bytes). Aliasing: xl2+xr2 fill xl1's region,
    //      h2 fills xr1's. h1 (fp16) is kept live through gemm2.
    uint8_t* w = (uint8_t*)d_ws;
    const size_t rowB = (size_t)n * 128 * 2;     // one N x 128 16-bit tensor
    __half*         xl1 = (__half*)w;
    __half*         xr1 = (__half*)(w + rowB);
    __half*         h1  = (__half*)(w + 2 * rowB);
    __half*         xl2 = (__half*)w;                           // n*64 fp16
    __half*         xr2 = (__half*)(w + (size_t)n * 64 * 2);
    float*          h2  = (float*)(w + rowB);                   // n*64 fp32
    uint8_t* fx = w + 3 * rowB;
    unsigned short* Wl1p = (unsigned short*)fx;            fx += 16384 * 2;
    unsigned short* Wr1p = (unsigned short*)fx;            fx += 16384 * 2;
    unsigned short* Wl2p = (unsigned short*)fx;            fx += 8192 * 2;
    unsigned short* Wr2p = (unsigned short*)fx;            fx += 8192 * 2;
    float* sl1 = (float*)fx;                               fx += (size_t)n * 2 * 4;
    float* sr1 = (float*)fx;                               fx += (size_t)n * 2 * 4;
    float* sl2 = (float*)fx;                               fx += (size_t)n * 4;
    float* sr2 = (float*)fx;                               fx += (size_t)n * 4;
    float* pooled = (float*)fx;                            fx += (size_t)NG * 64 * 4;
    float* counts = (float*)fx;                            fx += (size_t)NG * 4;
    int* cnt    = (int*)fx;                                fx += (size_t)n * 16 * 4;
    int* bucket = (int*)fx;                                fx += ((size_t)n * BCAP + 64) * 4;
    if (ws_size < (size_t)(fx - (uint8_t*)d_ws)) return;   // bail visibly

    const int GB  = (n + 63) / 64;       // gemm blocks (64 nodes each)
    const int FBn = (E + 1023) / 1024;   // fill blocks (4 edges/thread)
    const int ncnt = n * 16;             // spread counters (1 per 64B line)
    const int zcb = (ncnt + 255) / 256;
    const int npool = NG * 65;           // pooled + counts (contiguous)
    const int pzb = (npool + 255) / 256;
    const int dblocks = (n + 3) / 4;     // 4 dst-waves per 256-thread block
    const int T2 = 2 * ((GB > FBn) ? GB : FBn);

    // d1: pack weights + zero cnt + zero pooled/counts
    pack_zero<<<24 + zcb + pzb, 256, 0, stream>>>(Wl1, Wr1, Wl2, Wr2,
                                                  Wl1p, Wr1p, Wl2p, Wr2p,
                                                  cnt, ncnt, zcb, pooled, npool);
    // d2: gemm layer-1 || bucket fill, interleaved even/odd
    gemm1_fill<<<T2, 256, 0, stream>>>(x, Wl1p, Wr1p, xl1, xr1, att1,
                                       sl1, sr1, n, GB, FBn,
                                       srcA, dstA, E, cnt, bucket);
    // d3..d7
    gat1_fused<<<dblocks, 256, 0, stream>>>(xl1, xr1, sl1, sr1, att1,
                                            cnt, bucket, h1, n);
    gemm2<<<GB, 256, 0, stream>>>(h1, Wl2p, Wr2p, xl2, xr2, att2, b1, sl2, sr2, n);
    gat2_fused<<<dblocks, 256, 0, stream>>>(xl2, xr2, sl2, sr2, att2,
                                            cnt, bucket, h2, n);
    {
        const int nwaves = 1024;
        const int chunk = (n + nwaves - 1) / nwaves;
        pool_rle<<<256, 256, 0, stream>>>(h2, b2, batch, n, chunk, pooled, counts);
    }
    head<<<NG, 64, 0, stream>>>(pooled, counts, Wlin, blin, (float*)d_out, NC);
}

// Round 17
// 231.350 us; speedup vs baseline: 1.0902x; 1.0060x over previous
//
#include <hip/hip_runtime.h>
#include <hip/hip_fp16.h>
#include <cstdint>
#include <cstddef>

// ---------------------------------------------------------------------------
// GATv2Classifier: x(N,128) -> GATv2(2 heads,64,concat) -> elu
//                 -> GATv2(1 head,64) -> elu -> mean-pool(64 graphs) -> linear(10)
// R1..R10: pool rle; CSR->bucket gather; MFMA; edge-parallel fp16 score;
//          deferred bias/ELU; merged dispatches. 1368 -> 234us.
// R11-R15: fill probes (ILP, line-spread, co-located record, fence fusion):
//          all neutral/negative. Plateau 231-233us. Diagnosis: fill WRITE
//          ~41MB = 600k x 64B = ONE partial-line writeback PER 4B store,
//          because a node's ~12 stores come from ~12 different non-coherent
//          XCD L2s -- no combining possible across XCDs.
// R16: XCD-class-partitioned fill. Odd (fill) blocks map to XCDs {1,3,5,7}
//      under round-robin dispatch, cycling with f&3. Class c handles dst
//      slice d&3==c (scans all E, commits 1/4). All stores to a node's
//      bucket/cnt lines then come from ONE XCD -> combine in its L2.
//      Bucket stride 64 ints (256B, line-exclusive/node; slice 3.2MB < L2).
//      Perf heuristic only -- correctness independent of mapping.
// ---------------------------------------------------------------------------

typedef __attribute__((ext_vector_type(8))) short s8v;   // 8 bf16 (4 VGPRs)
typedef __attribute__((ext_vector_type(4))) float f4v;   // MFMA accumulator

#define LOG2E 1.44269504f

__device__ __forceinline__ unsigned short f2bf(float f) {
    unsigned u = __float_as_uint(f);
    unsigned r = (u + 0x7fffu + ((u >> 16) & 1u)) >> 16;   // RNE
    return (unsigned short)r;
}
__device__ __forceinline__ __half2 habs2_(__half2 x) {
    unsigned u; __builtin_memcpy(&u, &x, 4);
    u &= 0x7fff7fffu;
    __half2 r; __builtin_memcpy(&r, &u, 4);
    return r;
}
__device__ __forceinline__ float elu_(float v) {          // exp-based ELU
    return v > 0.f ? v : exp2f(v * LOG2E) - 1.f;
}
union U4H { uint4 u; __half2 h[4]; };

// ---- dual MFMA GEMM body (transposed): mfma(Wfrag,Xfrag) => D[outch][node]
template<int CO, bool ELU_A>
__device__ __forceinline__ void gemm_dual_body(
        int blk, const void* __restrict__ Aptr,
        const unsigned short* __restrict__ Wlp, const unsigned short* __restrict__ Wrp,
        __half* __restrict__ outL, __half* __restrict__ outR,
        const float* __restrict__ att, const float* __restrict__ bias_in,
        float* __restrict__ sl06, float* __restrict__ sr06, int n) {
    constexpr int NT = CO / 16;
    constexpr int H  = CO / 64;          // heads (2 layer1, 1 layer2)
    int lane = threadIdx.x & 63;
    int node0 = blk * 64 + (threadIdx.x >> 6) * 16;
    int m = lane & 15, quad = lane >> 4;
    int row = node0 + m;                 // node this lane loads AND owns in D
    s8v a[4];
#pragma unroll
    for (int ks = 0; ks < 4; ks++) {
        union { s8v v; unsigned short u[8]; } t;
        int k0 = ks * 32 + quad * 8;
        if (row < n) {
            if (ELU_A) {
                const __half* A = (const __half*)Aptr;
                U4H raw; raw.u = *(const uint4*)(A + ((unsigned)row << 7) + k0);
                float4 bA = *(const float4*)(bias_in + k0);
                float4 bB = *(const float4*)(bias_in + k0 + 4);
                float bb[8] = {bA.x, bA.y, bA.z, bA.w, bB.x, bB.y, bB.z, bB.w};
#pragma unroll
                for (int jp = 0; jp < 4; jp++) {
                    float e0 = elu_(__low2float(raw.h[jp])  + bb[jp * 2]);
                    float e1 = elu_(__high2float(raw.h[jp]) + bb[jp * 2 + 1]);
                    t.u[jp * 2]     = f2bf(e0);
                    t.u[jp * 2 + 1] = f2bf(e1);
                }
            } else {
                const float* A = (const float*)Aptr;
                float4 fA = *(const float4*)(A + ((unsigned)row << 7) + k0);
                float4 fB = *(const float4*)(A + ((unsigned)row << 7) + k0 + 4);
                t.u[0] = f2bf(fA.x); t.u[1] = f2bf(fA.y);
                t.u[2] = f2bf(fA.z); t.u[3] = f2bf(fA.w);
                t.u[4] = f2bf(fB.x); t.u[5] = f2bf(fB.y);
                t.u[6] = f2bf(fB.z); t.u[7] = f2bf(fB.w);
            }
        } else {
#pragma unroll
            for (int j = 0; j < 8; j++) t.u[j] = 0;
        }
        a[ks] = t.v;
    }
    float dl[2] = {0.f, 0.f}, dr[2] = {0.f, 0.f};   // per-head att-dot partials
#pragma unroll
    for (int ct = 0; ct < NT; ct++) {
        f4v cl = {0.f, 0.f, 0.f, 0.f}, cr = {0.f, 0.f, 0.f, 0.f};
#pragma unroll
        for (int ks = 0; ks < 4; ks++) {
            s8v bl = *(const s8v*)(Wlp + ((size_t)(ct * 4 + ks) * 64 + lane) * 8);
            s8v br = *(const s8v*)(Wrp + ((size_t)(ct * 4 + ks) * 64 + lane) * 8);
            cl = __builtin_amdgcn_mfma_f32_16x16x32_bf16(bl, a[ks], cl, 0, 0, 0);  // SWAPPED
            cr = __builtin_amdgcn_mfma_f32_16x16x32_bf16(br, a[ks], cr, 0, 0, 0);
        }
        int ch0 = ct * 16 + quad * 4;    // 4 consecutive out-channels this lane holds
        int hh = (H == 2) ? (ct >> 2) : 0;
        float4 av = *(const float4*)(att + ch0);
        dl[hh] += av.x * cl[0] + av.y * cl[1] + av.z * cl[2] + av.w * cl[3];
        dr[hh] += av.x * cr[0] + av.y * cr[1] + av.z * cr[2] + av.w * cr[3];
        if (row < n) {
            __half2 p0 = __floats2half2_rn(cl[0], cl[1]);
            __half2 p1 = __floats2half2_rn(cl[2], cl[3]);
            __half2 q0 = __floats2half2_rn(cr[0], cr[1]);
            __half2 q1 = __floats2half2_rn(cr[2], cr[3]);
            uint2 ov, orv;
            __builtin_memcpy(&ov.x, &p0, 4);  __builtin_memcpy(&ov.y, &p1, 4);
            __builtin_memcpy(&orv.x, &q0, 4); __builtin_memcpy(&orv.y, &q1, 4);
            *(uint2*)(outL + (unsigned)row * CO + ch0) = ov;
            *(uint2*)(outR + (unsigned)row * CO + ch0) = orv;
        }
    }
#pragma unroll
    for (int h = 0; h < H; h++) {
        float vl = dl[h], vr = dr[h];
        vl += __shfl_xor(vl, 16, 64); vl += __shfl_xor(vl, 32, 64);
        vr += __shfl_xor(vr, 16, 64); vr += __shfl_xor(vr, 32, 64);
        if (quad == 0 && row < n) {
            if (H == 2) {
                sl06[((unsigned)row << 1) + h] = (0.6f * LOG2E) * vl;
                sr06[((unsigned)row << 1) + h] = (0.6f * LOG2E) * vr;
            } else {
                sl06[row] = (0.6f * LOG2E) * vl;
                sr06[row] = (0.6f * LOG2E) * vr;
            }
        }
    }
}

// ---------------- d1: weight packing + zero(cnt,spread) + zero(pooled) ------
__global__ void pack_zero(const float* __restrict__ Wl1, const float* __restrict__ Wr1,
                          const float* __restrict__ Wl2, const float* __restrict__ Wr2,
                          unsigned short* __restrict__ Wl1p, unsigned short* __restrict__ Wr1p,
                          unsigned short* __restrict__ Wl2p, unsigned short* __restrict__ Wr2p,
                          int* __restrict__ cnt, int ncnt, int zcb,
                          float* __restrict__ pooled, int npool) {
    int b = blockIdx.x;
    if (b >= 24) {
        if (b < 24 + zcb) {
            int i = (b - 24) * 256 + threadIdx.x;
            if (i < ncnt) cnt[i] = 0;
        } else {
            int i = (b - 24 - zcb) * 256 + threadIdx.x;
            if (i < npool) pooled[i] = 0.f;
        }
        return;
    }
    int t = b * 256 + threadIdx.x;
    const float* W; unsigned short* Wp; int CO, base;
    if      (t < 2048) { W = Wl1; Wp = Wl1p; CO = 128; base = t; }
    else if (t < 4096) { W = Wr1; Wp = Wr1p; CO = 128; base = t - 2048; }
    else if (t < 5120) { W = Wl2; Wp = Wl2p; CO = 64;  base = t - 4096; }
    else               { W = Wr2; Wp = Wr2p; CO = 64;  base = t - 5120; }
    int lane = base & 63, ks = (base >> 6) & 3, ct = base >> 8;
    int col = ct * 16 + (lane & 15);
    int k0 = ks * 32 + (lane >> 4) * 8;
    unsigned short u[8];
#pragma unroll
    for (int j = 0; j < 8; j++) u[j] = f2bf(W[(size_t)(k0 + j) * CO + col]);
    unsigned* dst = (unsigned*)(Wp + (size_t)base * 8);
    dst[0] = u[0] | ((unsigned)u[1] << 16);
    dst[1] = u[2] | ((unsigned)u[3] << 16);
    dst[2] = u[4] | ((unsigned)u[5] << 16);
    dst[3] = u[6] | ((unsigned)u[7] << 16);
}

// ---------------- d2: interleaved gemm1 (even blocks) + fill (odd blocks) ---
// Fill class c = f&3 (odd blocks land on XCDs {1,3,5,7} under round-robin,
// cycling with f&3). Class c scans all E edges, commits only (d&3)==c:
// all stores to a node's bucket/cnt lines come from ONE XCD -> L2 combine.
__global__ void gemm1_fill(const float* __restrict__ x,
                           const unsigned short* __restrict__ Wl1p,
                           const unsigned short* __restrict__ Wr1p,
                           __half* __restrict__ xl1, __half* __restrict__ xr1,
                           const float* __restrict__ att1,
                           float* __restrict__ sl1, float* __restrict__ sr1, int n,
                           int GB, int FBn,
                           const int* __restrict__ srcA, const int* __restrict__ dstA, int E,
                           int* __restrict__ cnt, int* __restrict__ bucket) {
    int b = blockIdx.x;
    if ((b & 1) == 0) {
        int g = b >> 1;
        if (g < GB)
            gemm_dual_body<128, false>(g, x, Wl1p, Wr1p, xl1, xr1,
                                       att1, nullptr, sl1, sr1, n);
        return;
    }
    int f = b >> 1;
    if (f >= FBn) return;
    int c  = f & 3;                     // dst slice this block commits
    int r  = f >> 2;                    // rank within class
    int Rc = FBn >> 2;                  // blocks per class
    for (int i = r * 256 + (int)threadIdx.x; i < E; i += Rc * 256) {
        int d = dstA[i];
        if ((d & 3) == c) {
            int pos = atomicAdd(&cnt[d << 4], 1);   // deg<=~35 << 64 capacity
            bucket[(d << 6) + pos] = srcA[i];
        }
    }
}

__global__ void gemm2(const __half* __restrict__ h1,
                      const unsigned short* __restrict__ Wl2p,
                      const unsigned short* __restrict__ Wr2p,
                      __half* __restrict__ xl2, __half* __restrict__ xr2,
                      const float* __restrict__ att2, const float* __restrict__ b1,
                      float* __restrict__ sl2, float* __restrict__ sr2, int n) {
    gemm_dual_body<64, true>(blockIdx.x, h1, Wl2p, Wr2p, xl2, xr2,
                             att2, b1, sl2, sr2, n);
}

// ---------------- fused GATv2 layer 1: 4 edges/iter, 2-stage pipeline -------
__global__ void gat1_fused(const __half* __restrict__ xl, const __half* __restrict__ xr,
                           const float* __restrict__ sl06, const float* __restrict__ sr06,
                           const float* __restrict__ att,
                           const int* __restrict__ cnt, const int* __restrict__ bucket,
                           __half* __restrict__ h1, int n) {
    int d = (blockIdx.x * blockDim.x + threadIdx.x) >> 6;
    if (d >= n) return;
    int lane = threadIdx.x & 63;
    int e = lane >> 4;                  // edge slot 0..3
    int h = (lane >> 3) & 1;            // head
    int off = h * 64 + (lane & 7) * 8;  // 8-channel base
    U4H xv; xv.u = *(const uint4*)(xr + (((unsigned)d << 7) + off));
    float4 aA = *(const float4*)(att + off);
    float4 aB = *(const float4*)(att + off + 4);
    const float S = 0.4f * LOG2E;
    __half2 a2[4];
    a2[0] = __floats2half2_rn(S * aA.x, S * aA.y);
    a2[1] = __floats2half2_rn(S * aA.z, S * aA.w);
    a2[2] = __floats2half2_rn(S * aB.x, S * aB.y);
    a2[3] = __floats2half2_rn(S * aB.z, S * aB.w);
    float srd = sr06[((unsigned)d << 1) + h];
    float c0 = 0.f, c1 = 0.f, c2 = 0.f, c3 = 0.f;
    float c4 = 0.f, c5 = 0.f, c6 = 0.f, c7 = 0.f, den = 0.f;
    int deg = cnt[d << 4];
    int bb = d << 6;                    // 64-int (256B) stride, line-exclusive
    int j0 = -1 + e;
    int s0 = bucket[bb + max(j0, 0)];           s0 = (j0 >= 0 && j0 < deg) ? s0 : d;
    int j1 = j0 + 4;
    int s1 = bucket[bb + min(max(j1, 0), 63)];  s1 = (j1 >= 0 && j1 < deg) ? s1 : d;
    int j2 = j0 + 8;
    int s2 = bucket[bb + min(max(j2, 0), 63)];  s2 = (j2 >= 0 && j2 < deg) ? s2 : d;
    U4H xc;  xc.u  = *(const uint4*)(xl + (((unsigned)s0 << 7) + off));
    float slc = sl06[((unsigned)s0 << 1) + h];
    U4H xn1; xn1.u = *(const uint4*)(xl + (((unsigned)s1 << 7) + off));
    float sln1 = sl06[((unsigned)s1 << 1) + h];
    for (int base = -1; base < deg; base += 4) {
        U4H xn2; xn2.u = *(const uint4*)(xl + (((unsigned)s2 << 7) + off));
        float sln2 = sl06[((unsigned)s2 << 1) + h];
        int j3 = base + 12 + e;
        int s3 = bucket[bb + min(max(j3, 0), 63)];
        s3 = (j3 >= 0 && j3 < deg) ? s3 : d;
        bool valid = (base + e) < deg;
        __half2 sc = __floats2half2_rn(0.f, 0.f);
        sc = __hfma2(a2[0], habs2_(__hadd2(xc.h[0], xv.h[0])), sc);
        sc = __hfma2(a2[1], habs2_(__hadd2(xc.h[1], xv.h[1])), sc);
        sc = __hfma2(a2[2], habs2_(__hadd2(xc.h[2], xv.h[2])), sc);
        sc = __hfma2(a2[3], habs2_(__hadd2(xc.h[3], xv.h[3])), sc);
        float v = __low2float(sc) + __high2float(sc);
        v += __shfl_xor(v, 1, 64); v += __shfl_xor(v, 2, 64); v += __shfl_xor(v, 4, 64);
        float p = valid ? exp2f(slc + srd + v) : 0.f;
        c0 = fmaf(__low2float(xc.h[0]),  p, c0);
        c1 = fmaf(__high2float(xc.h[0]), p, c1);
        c2 = fmaf(__low2float(xc.h[1]),  p, c2);
        c3 = fmaf(__high2float(xc.h[1]), p, c3);
        c4 = fmaf(__low2float(xc.h[2]),  p, c4);
        c5 = fmaf(__high2float(xc.h[2]), p, c5);
        c6 = fmaf(__low2float(xc.h[3]),  p, c6);
        c7 = fmaf(__high2float(xc.h[3]), p, c7);
        den += p;
        xc = xn1; slc = sln1; xn1 = xn2; sln1 = sln2; s2 = s3;
    }
#pragma unroll
    for (int o = 16; o <= 32; o <<= 1) {
        c0 += __shfl_xor(c0, o, 64); c1 += __shfl_xor(c1, o, 64);
        c2 += __shfl_xor(c2, o, 64); c3 += __shfl_xor(c3, o, 64);
        c4 += __shfl_xor(c4, o, 64); c5 += __shfl_xor(c5, o, 64);
        c6 += __shfl_xor(c6, o, 64); c7 += __shfl_xor(c7, o, 64);
        den += __shfl_xor(den, o, 64);
    }
    if (e == 0) {
        float r = 1.f / den;
        __half2 o0 = __floats2half2_rn(c0 * r, c1 * r);
        __half2 o1 = __floats2half2_rn(c2 * r, c3 * r);
        __half2 o2 = __floats2half2_rn(c4 * r, c5 * r);
        __half2 o3 = __floats2half2_rn(c6 * r, c7 * r);
        uint4 out;
        __builtin_memcpy(&out.x, &o0, 4); __builtin_memcpy(&out.y, &o1, 4);
        __builtin_memcpy(&out.z, &o2, 4); __builtin_memcpy(&out.w, &o3, 4);
        *(uint4*)(h1 + (((unsigned)d << 7) + off)) = out;
    }
}

// ---------------- fused GATv2 layer 2: 8 edges/iter, 2-stage pipeline -------
__global__ void gat2_fused(const __half* __restrict__ xl, const __half* __restrict__ xr,
                           const float* __restrict__ sl06, const float* __restrict__ sr06,
                           const float* __restrict__ att,
                           const int* __restrict__ cnt, const int* __restrict__ bucket,
                           float* __restrict__ h2, int n) {
    int d = (blockIdx.x * blockDim.x + threadIdx.x) >> 6;
    if (d >= n) return;
    int lane = threadIdx.x & 63;
    int e = lane >> 3;                  // edge slot 0..7
    int off = (lane & 7) * 8;           // 8-channel base
    U4H xv; xv.u = *(const uint4*)(xr + (((unsigned)d << 6) + off));
    float4 aA = *(const float4*)(att + off);
    float4 aB = *(const float4*)(att + off + 4);
    const float S = 0.4f * LOG2E;
    __half2 a2[4];
    a2[0] = __floats2half2_rn(S * aA.x, S * aA.y);
    a2[1] = __floats2half2_rn(S * aA.z, S * aA.w);
    a2[2] = __floats2half2_rn(S * aB.x, S * aB.y);
    a2[3] = __floats2half2_rn(S * aB.z, S * aB.w);
    float srd = sr06[d];
    float c0 = 0.f, c1 = 0.f, c2 = 0.f, c3 = 0.f;
    float c4 = 0.f, c5 = 0.f, c6 = 0.f, c7 = 0.f, den = 0.f;
    int deg = cnt[d << 4];
    int bb = d << 6;
    int j0 = -1 + e;
    int s0 = bucket[bb + max(j0, 0)];           s0 = (j0 >= 0 && j0 < deg) ? s0 : d;
    int j1 = j0 + 8;
    int s1 = bucket[bb + min(max(j1, 0), 63)];  s1 = (j1 >= 0 && j1 < deg) ? s1 : d;
    int j2 = j0 + 16;
    int s2 = bucket[bb + min(max(j2, 0), 63)];  s2 = (j2 >= 0 && j2 < deg) ? s2 : d;
    U4H xc;  xc.u  = *(const uint4*)(xl + (((unsigned)s0 << 6) + off));
    float slc = sl06[s0];
    U4H xn1; xn1.u = *(const uint4*)(xl + (((unsigned)s1 << 6) + off));
    float sln1 = sl06[s1];
    for (int base = -1; base < deg; base += 8) {
        U4H xn2; xn2.u = *(const uint4*)(xl + (((unsigned)s2 << 6) + off));
        float sln2 = sl06[s2];
        int j3 = base + 24 + e;
        int s3 = bucket[bb + min(max(j3, 0), 63)];
        s3 = (j3 >= 0 && j3 < deg) ? s3 : d;
        bool valid = (base + e) < deg;
        __half2 sc = __floats2half2_rn(0.f, 0.f);
        sc = __hfma2(a2[0], habs2_(__hadd2(xc.h[0], xv.h[0])), sc);
        sc = __hfma2(a2[1], habs2_(__hadd2(xc.h[1], xv.h[1])), sc);
        sc = __hfma2(a2[2], habs2_(__hadd2(xc.h[2], xv.h[2])), sc);
        sc = __hfma2(a2[3], habs2_(__hadd2(xc.h[3], xv.h[3])), sc);
        float v = __low2float(sc) + __high2float(sc);
        v += __shfl_xor(v, 1, 64); v += __shfl_xor(v, 2, 64); v += __shfl_xor(v, 4, 64);
        float p = valid ? exp2f(slc + srd + v) : 0.f;
        c0 = fmaf(__low2float(xc.h[0]),  p, c0);
        c1 = fmaf(__high2float(xc.h[0]), p, c1);
        c2 = fmaf(__low2float(xc.h[1]),  p, c2);
        c3 = fmaf(__high2float(xc.h[1]), p, c3);
        c4 = fmaf(__low2float(xc.h[2]),  p, c4);
        c5 = fmaf(__high2float(xc.h[2]), p, c5);
        c6 = fmaf(__low2float(xc.h[3]),  p, c6);
        c7 = fmaf(__high2float(xc.h[3]), p, c7);
        den += p;
        xc = xn1; slc = sln1; xn1 = xn2; sln1 = sln2; s2 = s3;
    }
#pragma unroll
    for (int o = 8; o <= 32; o <<= 1) {
        c0 += __shfl_xor(c0, o, 64); c1 += __shfl_xor(c1, o, 64);
        c2 += __shfl_xor(c2, o, 64); c3 += __shfl_xor(c3, o, 64);
        c4 += __shfl_xor(c4, o, 64); c5 += __shfl_xor(c5, o, 64);
        c6 += __shfl_xor(c6, o, 64); c7 += __shfl_xor(c7, o, 64);
        den += __shfl_xor(den, o, 64);
    }
    if (e == 0) {
        float r = 1.f / den;
        float4 A = {c0 * r, c1 * r, c2 * r, c3 * r};
        float4 B = {c4 * r, c5 * r, c6 * r, c7 * r};
        *(float4*)(h2 + (((unsigned)d << 6) + off))     = A;
        *(float4*)(h2 + (((unsigned)d << 6) + off + 4)) = B;
    }
}

// mean-pool over sorted batch; applies deferred elu(h + b2) while reading.
__global__ void pool_rle(const float* __restrict__ h, const float* __restrict__ b2,
                         const int* __restrict__ batch,
                         int n, int chunk, float* __restrict__ pooled,
                         float* __restrict__ counts) {
    int w = (blockIdx.x * blockDim.x + threadIdx.x) >> 6;
    int lane = threadIdx.x & 63;
    int start = w * chunk;
    int end = min(n, start + chunk);
    if (start >= end) return;
    float bv = b2[lane];
    int cur = batch[start];
    float acc = 0.f, cnt = 0.f;
    for (int node = start; node < end; node++) {
        int g = batch[node];
        if (g != cur) {
            atomicAdd(&pooled[(size_t)cur * 64 + lane], acc);
            if (lane == 0) atomicAdd(&counts[cur], cnt);
            acc = 0.f; cnt = 0.f; cur = g;
        }
        acc += elu_(h[((unsigned)node << 6) + lane] + bv);
        cnt += 1.f;
    }
    atomicAdd(&pooled[(size_t)cur * 64 + lane], acc);
    if (lane == 0) atomicAdd(&counts[cur], cnt);
}

__global__ void head(const float* __restrict__ pooled, const float* __restrict__ counts,
                     const float* __restrict__ Wlin, const float* __restrict__ blin,
                     float* __restrict__ out, int NC) {
    int g = blockIdx.x;
    int lane = threadIdx.x;
    float cnt = fmaxf(counts[g], 1.f);
    float v = pooled[(size_t)g * 64 + lane] / cnt;
    for (int j = 0; j < NC; j++) {
        float t = v * Wlin[lane * NC + j];
        for (int off = 32; off > 0; off >>= 1) t += __shfl_down(t, off, 64);
        if (lane == 0) out[g * NC + j] = t + blin[j];
    }
}

extern "C" void kernel_launch(void* const* d_in, const int* in_sizes, int n_in,
                              void* d_out, int out_size, void* d_ws, size_t ws_size,
                              hipStream_t stream) {
    const float* x    = (const float*)d_in[0];
    const int*   ei   = (const int*)d_in[1];
    const int*   batch= (const int*)d_in[2];
    const float* Wl1  = (const float*)d_in[3];
    const float* Wr1  = (const float*)d_in[4];
    const float* att1 = (const float*)d_in[5];
    const float* b1   = (const float*)d_in[6];
    const float* Wl2  = (const float*)d_in[7];
    const float* Wr2  = (const float*)d_in[8];
    const float* att2 = (const float*)d_in[9];
    const float* b2   = (const float*)d_in[10];
    const float* Wlin = (const float*)d_in[11];
    const float* blin = (const float*)d_in[12];

    const int n    = in_sizes[0] / 128;   // 50000
    const int E    = in_sizes[1] / 2;     // 600000
    const int NC   = in_sizes[12];        // 10
    const int NG   = out_size / NC;       // 64

    const int* srcA = ei;
    const int* dstA = ei + E;

    // ---- workspace layout (bytes). Aliasing: xl2+xr2 fill xl1's region,
    //      h2 fills xr1's. h1 (fp16) is kept live through gemm2.
    uint8_t* w = (uint8_t*)d_ws;
    const size_t rowB = (size_t)n * 128 * 2;     // one N x 128 16-bit tensor
    __half*         xl1 = (__half*)w;
    __half*         xr1 = (__half*)(w + rowB);
    __half*         h1  = (__half*)(w + 2 * rowB);
    __half*         xl2 = (__half*)w;                           // n*64 fp16
    __half*         xr2 = (__half*)(w + (size_t)n * 64 * 2);
    float*          h2  = (float*)(w + rowB);                   // n*64 fp32
    uint8_t* fx = w + 3 * rowB;
    unsigned short* Wl1p = (unsigned short*)fx;            fx += 16384 * 2;
    unsigned short* Wr1p = (unsigned short*)fx;            fx += 16384 * 2;
    unsigned short* Wl2p = (unsigned short*)fx;            fx += 8192 * 2;
    unsigned short* Wr2p = (unsigned short*)fx;            fx += 8192 * 2;
    float* sl1 = (float*)fx;                               fx += (size_t)n * 2 * 4;
    float* sr1 = (float*)fx;                               fx += (size_t)n * 2 * 4;
    float* sl2 = (float*)fx;                               fx += (size_t)n * 4;
    float* sr2 = (float*)fx;                               fx += (size_t)n * 4;
    float* pooled = (float*)fx;                            fx += (size_t)NG * 64 * 4;
    float* counts = (float*)fx;                            fx += (size_t)NG * 4;
    fx = (uint8_t*)(((uintptr_t)fx + 255) & ~(uintptr_t)255);   // line-align
    int* cnt    = (int*)fx;                                fx += (size_t)n * 16 * 4;
    int* bucket = (int*)fx;                                fx += (size_t)n * 64 * 4 + 256;
    if (ws_size < (size_t)(fx - (uint8_t*)d_ws)) return;   // bail visibly

    const int GB  = (n + 63) / 64;       // gemm blocks (64 nodes each)
    const int FBn = 512;                 // fill blocks (4 classes x 128)
    const int ncnt = n * 16;             // spread counters (1 per 64B line)
    const int zcb = (ncnt + 255) / 256;
    const int npool = NG * 65;           // pooled + counts (contiguous)
    const int pzb = (npool + 255) / 256;
    const int dblocks = (n + 3) / 4;     // 4 dst-waves per 256-thread block
    const int T2 = 2 * ((GB > FBn) ? GB : FBn);

    // d1: pack weights + zero cnt + zero pooled/counts
    pack_zero<<<24 + zcb + pzb, 256, 0, stream>>>(Wl1, Wr1, Wl2, Wr2,
                                                  Wl1p, Wr1p, Wl2p, Wr2p,
                                                  cnt, ncnt, zcb, pooled, npool);
    // d2: gemm layer-1 || XCD-class-partitioned bucket fill
    gemm1_fill<<<T2, 256, 0, stream>>>(x, Wl1p, Wr1p, xl1, xr1, att1,
                                       sl1, sr1, n, GB, FBn,
                                       srcA, dstA, E, cnt, bucket);
    // d3..d7
    gat1_fused<<<dblocks, 256, 0, stream>>>(xl1, xr1, sl1, sr1, att1,
                                            cnt, bucket, h1, n);
    gemm2<<<GB, 256, 0, stream>>>(h1, Wl2p, Wr2p, xl2, xr2, att2, b1, sl2, sr2, n);
    gat2_fused<<<dblocks, 256, 0, stream>>>(xl2, xr2, sl2, sr2, att2,
                                            cnt, bucket, h2, n);
    {
        const int nwaves = 1024;
        const int chunk = (n + nwaves - 1) / nwaves;
        pool_rle<<<256, 256, 0, stream>>>(h2, b2, batch, n, chunk, pooled, counts);
    }
    head<<<NG, 64, 0, stream>>>(pooled, counts, Wlin, blin, (float*)d_out, NC);
}

// Round 18
// 230.217 us; speedup vs baseline: 1.0955x; 1.0049x over previous
//
#include <hip/hip_runtime.h>
#include <hip/hip_fp16.h>
#include <cstdint>
#include <cstddef>

// ---------------------------------------------------------------------------
// GATv2Classifier: x(N,128) -> GATv2(2 heads,64,concat) -> elu
//                 -> GATv2(1 head,64) -> elu -> mean-pool(64 graphs) -> linear(10)
// R1..R10: pool rle; bucket gather; MFMA; edge-parallel fp16 score;
//          deferred bias/ELU; merged dispatches. 1368 -> 234us.
// R11-R16: fill probes (ILP, line-spread, record co-location, fence fusion,
//          XCD-class partition): cumulative ~0. Plateau ~231us. Fill scatter
//          write-amp is irreducible (combining window << eviction in 4MB L2).
// R17: last untested lever -- gat gather pipeline 2 -> 3 data stages
//      (4 gathers in flight/lane). R8's 1->2 deepening was worth ~18us;
//      gat1 sits ~3x over its BW floor. ~6 VGPRs extra, under the 64-VGPR
//      occupancy cliff.
// ---------------------------------------------------------------------------

typedef __attribute__((ext_vector_type(8))) short s8v;   // 8 bf16 (4 VGPRs)
typedef __attribute__((ext_vector_type(4))) float f4v;   // MFMA accumulator

#define LOG2E 1.44269504f

__device__ __forceinline__ unsigned short f2bf(float f) {
    unsigned u = __float_as_uint(f);
    unsigned r = (u + 0x7fffu + ((u >> 16) & 1u)) >> 16;   // RNE
    return (unsigned short)r;
}
__device__ __forceinline__ __half2 habs2_(__half2 x) {
    unsigned u; __builtin_memcpy(&u, &x, 4);
    u &= 0x7fff7fffu;
    __half2 r; __builtin_memcpy(&r, &u, 4);
    return r;
}
__device__ __forceinline__ float elu_(float v) {          // exp-based ELU
    return v > 0.f ? v : exp2f(v * LOG2E) - 1.f;
}
union U4H { uint4 u; __half2 h[4]; };

// ---- dual MFMA GEMM body (transposed): mfma(Wfrag,Xfrag) => D[outch][node]
template<int CO, bool ELU_A>
__device__ __forceinline__ void gemm_dual_body(
        int blk, const void* __restrict__ Aptr,
        const unsigned short* __restrict__ Wlp, const unsigned short* __restrict__ Wrp,
        __half* __restrict__ outL, __half* __restrict__ outR,
        const float* __restrict__ att, const float* __restrict__ bias_in,
        float* __restrict__ sl06, float* __restrict__ sr06, int n) {
    constexpr int NT = CO / 16;
    constexpr int H  = CO / 64;          // heads (2 layer1, 1 layer2)
    int lane = threadIdx.x & 63;
    int node0 = blk * 64 + (threadIdx.x >> 6) * 16;
    int m = lane & 15, quad = lane >> 4;
    int row = node0 + m;                 // node this lane loads AND owns in D
    s8v a[4];
#pragma unroll
    for (int ks = 0; ks < 4; ks++) {
        union { s8v v; unsigned short u[8]; } t;
        int k0 = ks * 32 + quad * 8;
        if (row < n) {
            if (ELU_A) {
                const __half* A = (const __half*)Aptr;
                U4H raw; raw.u = *(const uint4*)(A + ((unsigned)row << 7) + k0);
                float4 bA = *(const float4*)(bias_in + k0);
                float4 bB = *(const float4*)(bias_in + k0 + 4);
                float bb[8] = {bA.x, bA.y, bA.z, bA.w, bB.x, bB.y, bB.z, bB.w};
#pragma unroll
                for (int jp = 0; jp < 4; jp++) {
                    float e0 = elu_(__low2float(raw.h[jp])  + bb[jp * 2]);
                    float e1 = elu_(__high2float(raw.h[jp]) + bb[jp * 2 + 1]);
                    t.u[jp * 2]     = f2bf(e0);
                    t.u[jp * 2 + 1] = f2bf(e1);
                }
            } else {
                const float* A = (const float*)Aptr;
                float4 fA = *(const float4*)(A + ((unsigned)row << 7) + k0);
                float4 fB = *(const float4*)(A + ((unsigned)row << 7) + k0 + 4);
                t.u[0] = f2bf(fA.x); t.u[1] = f2bf(fA.y);
                t.u[2] = f2bf(fA.z); t.u[3] = f2bf(fA.w);
                t.u[4] = f2bf(fB.x); t.u[5] = f2bf(fB.y);
                t.u[6] = f2bf(fB.z); t.u[7] = f2bf(fB.w);
            }
        } else {
#pragma unroll
            for (int j = 0; j < 8; j++) t.u[j] = 0;
        }
        a[ks] = t.v;
    }
    float dl[2] = {0.f, 0.f}, dr[2] = {0.f, 0.f};   // per-head att-dot partials
#pragma unroll
    for (int ct = 0; ct < NT; ct++) {
        f4v cl = {0.f, 0.f, 0.f, 0.f}, cr = {0.f, 0.f, 0.f, 0.f};
#pragma unroll
        for (int ks = 0; ks < 4; ks++) {
            s8v bl = *(const s8v*)(Wlp + ((size_t)(ct * 4 + ks) * 64 + lane) * 8);
            s8v br = *(const s8v*)(Wrp + ((size_t)(ct * 4 + ks) * 64 + lane) * 8);
            cl = __builtin_amdgcn_mfma_f32_16x16x32_bf16(bl, a[ks], cl, 0, 0, 0);  // SWAPPED
            cr = __builtin_amdgcn_mfma_f32_16x16x32_bf16(br, a[ks], cr, 0, 0, 0);
        }
        int ch0 = ct * 16 + quad * 4;    // 4 consecutive out-channels this lane holds
        int hh = (H == 2) ? (ct >> 2) : 0;
        float4 av = *(const float4*)(att + ch0);
        dl[hh] += av.x * cl[0] + av.y * cl[1] + av.z * cl[2] + av.w * cl[3];
        dr[hh] += av.x * cr[0] + av.y * cr[1] + av.z * cr[2] + av.w * cr[3];
        if (row < n) {
            __half2 p0 = __floats2half2_rn(cl[0], cl[1]);
            __half2 p1 = __floats2half2_rn(cl[2], cl[3]);
            __half2 q0 = __floats2half2_rn(cr[0], cr[1]);
            __half2 q1 = __floats2half2_rn(cr[2], cr[3]);
            uint2 ov, orv;
            __builtin_memcpy(&ov.x, &p0, 4);  __builtin_memcpy(&ov.y, &p1, 4);
            __builtin_memcpy(&orv.x, &q0, 4); __builtin_memcpy(&orv.y, &q1, 4);
            *(uint2*)(outL + (unsigned)row * CO + ch0) = ov;
            *(uint2*)(outR + (unsigned)row * CO + ch0) = orv;
        }
    }
#pragma unroll
    for (int h = 0; h < H; h++) {
        float vl = dl[h], vr = dr[h];
        vl += __shfl_xor(vl, 16, 64); vl += __shfl_xor(vl, 32, 64);
        vr += __shfl_xor(vr, 16, 64); vr += __shfl_xor(vr, 32, 64);
        if (quad == 0 && row < n) {
            if (H == 2) {
                sl06[((unsigned)row << 1) + h] = (0.6f * LOG2E) * vl;
                sr06[((unsigned)row << 1) + h] = (0.6f * LOG2E) * vr;
            } else {
                sl06[row] = (0.6f * LOG2E) * vl;
                sr06[row] = (0.6f * LOG2E) * vr;
            }
        }
    }
}

// ---------------- d1: weight packing + zero(cnt,spread) + zero(pooled) ------
__global__ void pack_zero(const float* __restrict__ Wl1, const float* __restrict__ Wr1,
                          const float* __restrict__ Wl2, const float* __restrict__ Wr2,
                          unsigned short* __restrict__ Wl1p, unsigned short* __restrict__ Wr1p,
                          unsigned short* __restrict__ Wl2p, unsigned short* __restrict__ Wr2p,
                          int* __restrict__ cnt, int ncnt, int zcb,
                          float* __restrict__ pooled, int npool) {
    int b = blockIdx.x;
    if (b >= 24) {
        if (b < 24 + zcb) {
            int i = (b - 24) * 256 + threadIdx.x;
            if (i < ncnt) cnt[i] = 0;
        } else {
            int i = (b - 24 - zcb) * 256 + threadIdx.x;
            if (i < npool) pooled[i] = 0.f;
        }
        return;
    }
    int t = b * 256 + threadIdx.x;
    const float* W; unsigned short* Wp; int CO, base;
    if      (t < 2048) { W = Wl1; Wp = Wl1p; CO = 128; base = t; }
    else if (t < 4096) { W = Wr1; Wp = Wr1p; CO = 128; base = t - 2048; }
    else if (t < 5120) { W = Wl2; Wp = Wl2p; CO = 64;  base = t - 4096; }
    else               { W = Wr2; Wp = Wr2p; CO = 64;  base = t - 5120; }
    int lane = base & 63, ks = (base >> 6) & 3, ct = base >> 8;
    int col = ct * 16 + (lane & 15);
    int k0 = ks * 32 + (lane >> 4) * 8;
    unsigned short u[8];
#pragma unroll
    for (int j = 0; j < 8; j++) u[j] = f2bf(W[(size_t)(k0 + j) * CO + col]);
    unsigned* dst = (unsigned*)(Wp + (size_t)base * 8);
    dst[0] = u[0] | ((unsigned)u[1] << 16);
    dst[1] = u[2] | ((unsigned)u[3] << 16);
    dst[2] = u[4] | ((unsigned)u[5] << 16);
    dst[3] = u[6] | ((unsigned)u[7] << 16);
}

// ---------------- d2: interleaved gemm1 (even blocks) + fill (odd blocks) ---
// Fill class c = f&3: commits dst slice (d&3)==c (XCD-class write locality).
__global__ void gemm1_fill(const float* __restrict__ x,
                           const unsigned short* __restrict__ Wl1p,
                           const unsigned short* __restrict__ Wr1p,
                           __half* __restrict__ xl1, __half* __restrict__ xr1,
                           const float* __restrict__ att1,
                           float* __restrict__ sl1, float* __restrict__ sr1, int n,
                           int GB, int FBn,
                           const int* __restrict__ srcA, const int* __restrict__ dstA, int E,
                           int* __restrict__ cnt, int* __restrict__ bucket) {
    int b = blockIdx.x;
    if ((b & 1) == 0) {
        int g = b >> 1;
        if (g < GB)
            gemm_dual_body<128, false>(g, x, Wl1p, Wr1p, xl1, xr1,
                                       att1, nullptr, sl1, sr1, n);
        return;
    }
    int f = b >> 1;
    if (f >= FBn) return;
    int c  = f & 3;                     // dst slice this block commits
    int r  = f >> 2;                    // rank within class
    int Rc = FBn >> 2;                  // blocks per class
    for (int i = r * 256 + (int)threadIdx.x; i < E; i += Rc * 256) {
        int d = dstA[i];
        if ((d & 3) == c) {
            int pos = atomicAdd(&cnt[d << 4], 1);   // deg<=~35 << 64 capacity
            bucket[(d << 6) + pos] = srcA[i];
        }
    }
}

__global__ void gemm2(const __half* __restrict__ h1,
                      const unsigned short* __restrict__ Wl2p,
                      const unsigned short* __restrict__ Wr2p,
                      __half* __restrict__ xl2, __half* __restrict__ xr2,
                      const float* __restrict__ att2, const float* __restrict__ b1,
                      float* __restrict__ sl2, float* __restrict__ sr2, int n) {
    gemm_dual_body<64, true>(blockIdx.x, h1, Wl2p, Wr2p, xl2, xr2,
                             att2, b1, sl2, sr2, n);
}

// ---------------- fused GATv2 layer 1: 4 edges/iter, 3-stage pipeline -------
__global__ void gat1_fused(const __half* __restrict__ xl, const __half* __restrict__ xr,
                           const float* __restrict__ sl06, const float* __restrict__ sr06,
                           const float* __restrict__ att,
                           const int* __restrict__ cnt, const int* __restrict__ bucket,
                           __half* __restrict__ h1, int n) {
    int d = (blockIdx.x * blockDim.x + threadIdx.x) >> 6;
    if (d >= n) return;
    int lane = threadIdx.x & 63;
    int e = lane >> 4;                  // edge slot 0..3
    int h = (lane >> 3) & 1;            // head
    int off = h * 64 + (lane & 7) * 8;  // 8-channel base
    U4H xv; xv.u = *(const uint4*)(xr + (((unsigned)d << 7) + off));
    float4 aA = *(const float4*)(att + off);
    float4 aB = *(const float4*)(att + off + 4);
    const float S = 0.4f * LOG2E;
    __half2 a2[4];
    a2[0] = __floats2half2_rn(S * aA.x, S * aA.y);
    a2[1] = __floats2half2_rn(S * aA.z, S * aA.w);
    a2[2] = __floats2half2_rn(S * aB.x, S * aB.y);
    a2[3] = __floats2half2_rn(S * aB.z, S * aB.w);
    float srd = sr06[((unsigned)d << 1) + h];
    float c0 = 0.f, c1 = 0.f, c2 = 0.f, c3 = 0.f;
    float c4 = 0.f, c5 = 0.f, c6 = 0.f, c7 = 0.f, den = 0.f;
    int deg = cnt[d << 4];
    int bb = d << 6;                    // 64-int (256B) stride, line-exclusive
    int j0 = -1 + e;
    int s0 = bucket[bb + max(j0, 0)];           s0 = (j0 >= 0 && j0 < deg) ? s0 : d;
    int s1 = bucket[bb + min(max(j0 + 4, 0), 63)];
    s1 = (j0 + 4 >= 0 && j0 + 4 < deg) ? s1 : d;
    int s2 = bucket[bb + min(max(j0 + 8, 0), 63)];
    s2 = (j0 + 8 >= 0 && j0 + 8 < deg) ? s2 : d;
    int s3 = bucket[bb + min(max(j0 + 12, 0), 63)];
    s3 = (j0 + 12 >= 0 && j0 + 12 < deg) ? s3 : d;
    U4H xc;  xc.u  = *(const uint4*)(xl + (((unsigned)s0 << 7) + off));
    float slc = sl06[((unsigned)s0 << 1) + h];
    U4H xn1; xn1.u = *(const uint4*)(xl + (((unsigned)s1 << 7) + off));
    float sln1 = sl06[((unsigned)s1 << 1) + h];
    U4H xn2; xn2.u = *(const uint4*)(xl + (((unsigned)s2 << 7) + off));
    float sln2 = sl06[((unsigned)s2 << 1) + h];
    for (int base = -1; base < deg; base += 4) {
        // stage-3 prefetch: data for iter k+3's source, index for k+4
        U4H xn3; xn3.u = *(const uint4*)(xl + (((unsigned)s3 << 7) + off));
        float sln3 = sl06[((unsigned)s3 << 1) + h];
        int j4 = base + 16 + e;
        int s4 = bucket[bb + min(max(j4, 0), 63)];
        s4 = (j4 >= 0 && j4 < deg) ? s4 : d;
        bool valid = (base + e) < deg;
        __half2 sc = __floats2half2_rn(0.f, 0.f);
        sc = __hfma2(a2[0], habs2_(__hadd2(xc.h[0], xv.h[0])), sc);
        sc = __hfma2(a2[1], habs2_(__hadd2(xc.h[1], xv.h[1])), sc);
        sc = __hfma2(a2[2], habs2_(__hadd2(xc.h[2], xv.h[2])), sc);
        sc = __hfma2(a2[3], habs2_(__hadd2(xc.h[3], xv.h[3])), sc);
        float v = __low2float(sc) + __high2float(sc);
        v += __shfl_xor(v, 1, 64); v += __shfl_xor(v, 2, 64); v += __shfl_xor(v, 4, 64);
        float p = valid ? exp2f(slc + srd + v) : 0.f;
        c0 = fmaf(__low2float(xc.h[0]),  p, c0);
        c1 = fmaf(__high2float(xc.h[0]), p, c1);
        c2 = fmaf(__low2float(xc.h[1]),  p, c2);
        c3 = fmaf(__high2float(xc.h[1]), p, c3);
        c4 = fmaf(__low2float(xc.h[2]),  p, c4);
        c5 = fmaf(__high2float(xc.h[2]), p, c5);
        c6 = fmaf(__low2float(xc.h[3]),  p, c6);
        c7 = fmaf(__high2float(xc.h[3]), p, c7);
        den += p;
        xc = xn1; slc = sln1;
        xn1 = xn2; sln1 = sln2;
        xn2 = xn3; sln2 = sln3;
        s3 = s4;
    }
#pragma unroll
    for (int o = 16; o <= 32; o <<= 1) {
        c0 += __shfl_xor(c0, o, 64); c1 += __shfl_xor(c1, o, 64);
        c2 += __shfl_xor(c2, o, 64); c3 += __shfl_xor(c3, o, 64);
        c4 += __shfl_xor(c4, o, 64); c5 += __shfl_xor(c5, o, 64);
        c6 += __shfl_xor(c6, o, 64); c7 += __shfl_xor(c7, o, 64);
        den += __shfl_xor(den, o, 64);
    }
    if (e == 0) {
        float r = 1.f / den;
        __half2 o0 = __floats2half2_rn(c0 * r, c1 * r);
        __half2 o1 = __floats2half2_rn(c2 * r, c3 * r);
        __half2 o2 = __floats2half2_rn(c4 * r, c5 * r);
        __half2 o3 = __floats2half2_rn(c6 * r, c7 * r);
        uint4 out;
        __builtin_memcpy(&out.x, &o0, 4); __builtin_memcpy(&out.y, &o1, 4);
        __builtin_memcpy(&out.z, &o2, 4); __builtin_memcpy(&out.w, &o3, 4);
        *(uint4*)(h1 + (((unsigned)d << 7) + off)) = out;
    }
}

// ---------------- fused GATv2 layer 2: 8 edges/iter, 3-stage pipeline -------
__global__ void gat2_fused(const __half* __restrict__ xl, const __half* __restrict__ xr,
                           const float* __restrict__ sl06, const float* __restrict__ sr06,
                           const float* __restrict__ att,
                           const int* __restrict__ cnt, const int* __restrict__ bucket,
                           float* __restrict__ h2, int n) {
    int d = (blockIdx.x * blockDim.x + threadIdx.x) >> 6;
    if (d >= n) return;
    int lane = threadIdx.x & 63;
    int e = lane >> 3;                  // edge slot 0..7
    int off = (lane & 7) * 8;           // 8-channel base
    U4H xv; xv.u = *(const uint4*)(xr + (((unsigned)d << 6) + off));
    float4 aA = *(const float4*)(att + off);
    float4 aB = *(const float4*)(att + off + 4);
    const float S = 0.4f * LOG2E;
    __half2 a2[4];
    a2[0] = __floats2half2_rn(S * aA.x, S * aA.y);
    a2[1] = __floats2half2_rn(S * aA.z, S * aA.w);
    a2[2] = __floats2half2_rn(S * aB.x, S * aB.y);
    a2[3] = __floats2half2_rn(S * aB.z, S * aB.w);
    float srd = sr06[d];
    float c0 = 0.f, c1 = 0.f, c2 = 0.f, c3 = 0.f;
    float c4 = 0.f, c5 = 0.f, c6 = 0.f, c7 = 0.f, den = 0.f;
    int deg = cnt[d << 4];
    int bb = d << 6;
    int j0 = -1 + e;
    int s0 = bucket[bb + max(j0, 0)];           s0 = (j0 >= 0 && j0 < deg) ? s0 : d;
    int s1 = bucket[bb + min(max(j0 + 8, 0), 63)];
    s1 = (j0 + 8 >= 0 && j0 + 8 < deg) ? s1 : d;
    int s2 = bucket[bb + min(max(j0 + 16, 0), 63)];
    s2 = (j0 + 16 >= 0 && j0 + 16 < deg) ? s2 : d;
    int s3 = bucket[bb + min(max(j0 + 24, 0), 63)];
    s3 = (j0 + 24 >= 0 && j0 + 24 < deg) ? s3 : d;
    U4H xc;  xc.u  = *(const uint4*)(xl + (((unsigned)s0 << 6) + off));
    float slc = sl06[s0];
    U4H xn1; xn1.u = *(const uint4*)(xl + (((unsigned)s1 << 6) + off));
    float sln1 = sl06[s1];
    U4H xn2; xn2.u = *(const uint4*)(xl + (((unsigned)s2 << 6) + off));
    float sln2 = sl06[s2];
    for (int base = -1; base < deg; base += 8) {
        U4H xn3; xn3.u = *(const uint4*)(xl + (((unsigned)s3 << 6) + off));
        float sln3 = sl06[s3];
        int j4 = base + 32 + e;
        int s4 = bucket[bb + min(max(j4, 0), 63)];
        s4 = (j4 >= 0 && j4 < deg) ? s4 : d;
        bool valid = (base + e) < deg;
        __half2 sc = __floats2half2_rn(0.f, 0.f);
        sc = __hfma2(a2[0], habs2_(__hadd2(xc.h[0], xv.h[0])), sc);
        sc = __hfma2(a2[1], habs2_(__hadd2(xc.h[1], xv.h[1])), sc);
        sc = __hfma2(a2[2], habs2_(__hadd2(xc.h[2], xv.h[2])), sc);
        sc = __hfma2(a2[3], habs2_(__hadd2(xc.h[3], xv.h[3])), sc);
        float v = __low2float(sc) + __high2float(sc);
        v += __shfl_xor(v, 1, 64); v += __shfl_xor(v, 2, 64); v += __shfl_xor(v, 4, 64);
        float p = valid ? exp2f(slc + srd + v) : 0.f;
        c0 = fmaf(__low2float(xc.h[0]),  p, c0);
        c1 = fmaf(__high2float(xc.h[0]), p, c1);
        c2 = fmaf(__low2float(xc.h[1]),  p, c2);
        c3 = fmaf(__high2float(xc.h[1]), p, c3);
        c4 = fmaf(__low2float(xc.h[2]),  p, c4);
        c5 = fmaf(__high2float(xc.h[2]), p, c5);
        c6 = fmaf(__low2float(xc.h[3]),  p, c6);
        c7 = fmaf(__high2float(xc.h[3]), p, c7);
        den += p;
        xc = xn1; slc = sln1;
        xn1 = xn2; sln1 = sln2;
        xn2 = xn3; sln2 = sln3;
        s3 = s4;
    }
#pragma unroll
    for (int o = 8; o <= 32; o <<= 1) {
        c0 += __shfl_xor(c0, o, 64); c1 += __shfl_xor(c1, o, 64);
        c2 += __shfl_xor(c2, o, 64); c3 += __shfl_xor(c3, o, 64);
        c4 += __shfl_xor(c4, o, 64); c5 += __shfl_xor(c5, o, 64);
        c6 += __shfl_xor(c6, o, 64); c7 += __shfl_xor(c7, o, 64);
        den += __shfl_xor(den, o, 64);
    }
    if (e == 0) {
        float r = 1.f / den;
        float4 A = {c0 * r, c1 * r, c2 * r, c3 * r};
        float4 B = {c4 * r, c5 * r, c6 * r, c7 * r};
        *(float4*)(h2 + (((unsigned)d << 6) + off))     = A;
        *(float4*)(h2 + (((unsigned)d << 6) + off + 4)) = B;
    }
}

// mean-pool over sorted batch; applies deferred elu(h + b2) while reading.
__global__ void pool_rle(const float* __restrict__ h, const float* __restrict__ b2,
                         const int* __restrict__ batch,
                         int n, int chunk, float* __restrict__ pooled,
                         float* __restrict__ counts) {
    int w = (blockIdx.x * blockDim.x + threadIdx.x) >> 6;
    int lane = threadIdx.x & 63;
    int start = w * chunk;
    int end = min(n, start + chunk);
    if (start >= end) return;
    float bv = b2[lane];
    int cur = batch[start];
    float acc = 0.f, cnt = 0.f;
    for (int node = start; node < end; node++) {
        int g = batch[node];
        if (g != cur) {
            atomicAdd(&pooled[(size_t)cur * 64 + lane], acc);
            if (lane == 0) atomicAdd(&counts[cur], cnt);
            acc = 0.f; cnt = 0.f; cur = g;
        }
        acc += elu_(h[((unsigned)node << 6) + lane] + bv);
        cnt += 1.f;
    }
    atomicAdd(&pooled[(size_t)cur * 64 + lane], acc);
    if (lane == 0) atomicAdd(&counts[cur], cnt);
}

__global__ void head(const float* __restrict__ pooled, const float* __restrict__ counts,
                     const float* __restrict__ Wlin, const float* __restrict__ blin,
                     float* __restrict__ out, int NC) {
    int g = blockIdx.x;
    int lane = threadIdx.x;
    float cnt = fmaxf(counts[g], 1.f);
    float v = pooled[(size_t)g * 64 + lane] / cnt;
    for (int j = 0; j < NC; j++) {
        float t = v * Wlin[lane * NC + j];
        for (int off = 32; off > 0; off >>= 1) t += __shfl_down(t, off, 64);
        if (lane == 0) out[g * NC + j] = t + blin[j];
    }
}

extern "C" void kernel_launch(void* const* d_in, const int* in_sizes, int n_in,
                              void* d_out, int out_size, void* d_ws, size_t ws_size,
                              hipStream_t stream) {
    const float* x    = (const float*)d_in[0];
    const int*   ei   = (const int*)d_in[1];
    const int*   batch= (const int*)d_in[2];
    const float* Wl1  = (const float*)d_in[3];
    const float* Wr1  = (const float*)d_in[4];
    const float* att1 = (const float*)d_in[5];
    const float* b1   = (const float*)d_in[6];
    const float* Wl2  = (const float*)d_in[7];
    const float* Wr2  = (const float*)d_in[8];
    const float* att2 = (const float*)d_in[9];
    const float* b2   = (const float*)d_in[10];
    const float* Wlin = (const float*)d_in[11];
    const float* blin = (const float*)d_in[12];

    const int n    = in_sizes[0] / 128;   // 50000
    const int E    = in_sizes[1] / 2;     // 600000
    const int NC   = in_sizes[12];        // 10
    const int NG   = out_size / NC;       // 64

    const int* srcA = ei;
    const int* dstA = ei + E;

    // ---- workspace layout (bytes). Aliasing: xl2+xr2 fill xl1's region,
    //      h2 fills xr1's. h1 (fp16) is kept live through gemm2.
    uint8_t* w = (uint8_t*)d_ws;
    const size_t rowB = (size_t)n * 128 * 2;     // one N x 128 16-bit tensor
    __half*         xl1 = (__half*)w;
    __half*         xr1 = (__half*)(w + rowB);
    __half*         h1  = (__half*)(w + 2 * rowB);
    __half*         xl2 = (__half*)w;                           // n*64 fp16
    __half*         xr2 = (__half*)(w + (size_t)n * 64 * 2);
    float*          h2  = (float*)(w + rowB);                   // n*64 fp32
    uint8_t* fx = w + 3 * rowB;
    unsigned short* Wl1p = (unsigned short*)fx;            fx += 16384 * 2;
    unsigned short* Wr1p = (unsigned short*)fx;            fx += 16384 * 2;
    unsigned short* Wl2p = (unsigned short*)fx;            fx += 8192 * 2;
    unsigned short* Wr2p = (unsigned short*)fx;            fx += 8192 * 2;
    float* sl1 = (float*)fx;                               fx += (size_t)n * 2 * 4;
    float* sr1 = (float*)fx;                               fx += (size_t)n * 2 * 4;
    float* sl2 = (float*)fx;                               fx += (size_t)n * 4;
    float* sr2 = (float*)fx;                               fx += (size_t)n * 4;
    float* pooled = (float*)fx;                            fx += (size_t)NG * 64 * 4;
    float* counts = (float*)fx;                            fx += (size_t)NG * 4;
    fx = (uint8_t*)(((uintptr_t)fx + 255) & ~(uintptr_t)255);   // line-align
    int* cnt    = (int*)fx;                                fx += (size_t)n * 16 * 4;
    int* bucket = (int*)fx;                                fx += (size_t)n * 64 * 4 + 256;
    if (ws_size < (size_t)(fx - (uint8_t*)d_ws)) return;   // bail visibly

    const int GB  = (n + 63) / 64;       // gemm blocks (64 nodes each)
    const int FBn = 512;                 // fill blocks (4 classes x 128)
    const int ncnt = n * 16;             // spread counters (1 per 64B line)
    const int zcb = (ncnt + 255) / 256;
    const int npool = NG * 65;           // pooled + counts (contiguous)
    const int pzb = (npool + 255) / 256;
    const int dblocks = (n + 3) / 4;     // 4 dst-waves per 256-thread block
    const int T2 = 2 * ((GB > FBn) ? GB : FBn);

    // d1: pack weights + zero cnt + zero pooled/counts
    pack_zero<<<24 + zcb + pzb, 256, 0, stream>>>(Wl1, Wr1, Wl2, Wr2,
                                                  Wl1p, Wr1p, Wl2p, Wr2p,
                                                  cnt, ncnt, zcb, pooled, npool);
    // d2: gemm layer-1 || XCD-class-partitioned bucket fill
    gemm1_fill<<<T2, 256, 0, stream>>>(x, Wl1p, Wr1p, xl1, xr1, att1,
                                       sl1, sr1, n, GB, FBn,
                                       srcA, dstA, E, cnt, bucket);
    // d3..d7
    gat1_fused<<<dblocks, 256, 0, stream>>>(xl1, xr1, sl1, sr1, att1,
                                            cnt, bucket, h1, n);
    gemm2<<<GB, 256, 0, stream>>>(h1, Wl2p, Wr2p, xl2, xr2, att2, b1, sl2, sr2, n);
    gat2_fused<<<dblocks, 256, 0, stream>>>(xl2, xr2, sl2, sr2, att2,
                                            cnt, bucket, h2, n);
    {
        const int nwaves = 1024;
        const int chunk = (n + nwaves - 1) / nwaves;
        pool_rle<<<256, 256, 0, stream>>>(h2, b2, batch, n, chunk, pooled, counts);
    }
    head<<<NG, 64, 0, stream>>>(pooled, counts, Wlin, blin, (float*)d_out, NC);
}